// Round 6
// baseline (3981.496 us; speedup 1.0000x reference)
//
// RNN_79577154060490 — round 7: wave-autonomous flag sync (no per-step block
// barriers). h0 = p0@W_enc^T; 100x h=tanh(v@W_ih^T + h@W_hh^T); out = g@W_dec^T+b
//
// Round-6 post-mortem (947us loop, 9.5us/step, pass): cache-op elimination was
// right; residual is serialization — 4-5 __syncthreads/step force 8-wave
// lockstep so every LLC round-trip is paid serially by the slowest wave.
// Round-7: per-WAVE publication/waiting:
//  * producer wave: Part stores -> own vmcnt(0) -> pcnt[gt*4+mg] += 1 (16/step).
//  * reduce wave (gt,ks) needs only rows ks*16..+15 -> waits
//    pcnt[gt*4+(ks>>1)] >= 16(t+1)  (its 16 producers, not all 64).
//  * reduce wave: h atomics -> own vmcnt(0) -> hcnt[gt] += 1 (64/step).
//  * mm wave waits hcnt[ks*4+c] >= 64t (RAW, 4 chunks) + hcnt[gt] >= 64t (WAR).
//  * no __syncthreads in the t-loop at all; waves free-run and the CU scheduler
//    overlaps one wave's LLC latency with another's MFMA (m114).
//  * micro: Wih hoisted out of t-loop; v(t) prefetched before mm.
// Data movement (unchanged from round 6, verified): Part normal stores + sc0
// reads; h via agent-scope atomic-exchange (executes at LLC); A plain cached
// (first-touch per dispatch); W_hh LDS-resident.
//
// ws layout (bytes):
//   [0,         33554432)   WhS  bf16 [gt32][chunk32][nt8][ktl4][64][8]
//   [33554432,  37748736)   WdS  bf16 [pt4][chunk32][nt8][ktl4][64][8]
//   [37748736,  38797312)   H0S  bf16 A-image (1MB)
//   [38797312, 143654912)   Gsw  bf16 [t100] A-images (100MB)
//   [143654912,160432128)   Part fp32 [gt32][ks8][128][128] (16MB)
//   [160432128,160440320)   flags int[2048]: pcnt[128] stride 8; hcnt[32] stride 32 @ +1024

#include <hip/hip_runtime.h>
#include <stdint.h>

namespace {
constexpr int kT = 100;
constexpr int kNG = 4096;
constexpr int kNP = 512;

__device__ __forceinline__ uint16_t f2bf(float f) {
  uint32_t u = __float_as_uint(f);
  u += 0x7FFFu + ((u >> 16) & 1u);
  return (uint16_t)(u >> 16);
}

__device__ __forceinline__ float fast_tanh(float x) {
  float xc = fminf(fmaxf(x, -15.f), 15.f);
  float e = __expf(2.f * xc);
  return (e - 1.f) / (e + 1.f);
}

__device__ __forceinline__ void gl2lds16(const void* g, void* l) {
  __builtin_amdgcn_global_load_lds((const __attribute__((address_space(1))) unsigned int*)g,
                                   (__attribute__((address_space(3))) unsigned int*)l, 16, 0, 0);
}

// fragment-image element offsets (within one tensor)
__device__ __forceinline__ size_t a_img_off(int b, int g) {  // g = k index
  return ((size_t)(((g >> 7) * 8 + (b >> 4)) * 4 + ((g >> 5) & 3)) * 64 +
          ((g >> 3) & 3) * 16 + (b & 15)) * 8 + (g & 7);
}
}  // namespace

typedef short bf16x8 __attribute__((ext_vector_type(8)));
typedef float f32x4 __attribute__((ext_vector_type(4)));

// ---- swizzle-convert W_hh fp32 [4096][4096] -> WhS B-image bf16 (+flag zero) ----
__global__ __launch_bounds__(512) void cvt_whh_kernel(const float* __restrict__ W,
                                                      uint16_t* __restrict__ WhS,
                                                      int* __restrict__ flags) {
  if (blockIdx.x == 4095) {
    for (int i = threadIdx.x; i < 2048; i += 512) flags[i] = 0;
  }
  const int idx = blockIdx.x * 512 + threadIdx.x;  // 2M threads
  const int g = idx >> 9;
  const int k0 = (idx & 511) << 3;
  const float4 x = *(const float4*)(W + (size_t)g * kNG + k0);
  const float4 y = *(const float4*)(W + (size_t)g * kNG + k0 + 4);
  uint4 u;
  u.x = (uint32_t)f2bf(x.x) | ((uint32_t)f2bf(x.y) << 16);
  u.y = (uint32_t)f2bf(x.z) | ((uint32_t)f2bf(x.w) << 16);
  u.z = (uint32_t)f2bf(y.x) | ((uint32_t)f2bf(y.y) << 16);
  u.w = (uint32_t)f2bf(y.z) | ((uint32_t)f2bf(y.w) << 16);
  const int gt = g >> 7, c = g & 127;
  const int nt = c >> 4, col = c & 15;
  const int chunk = k0 >> 7, ktl = (k0 >> 5) & 3, half = (k0 >> 3) & 3;
  const size_t off = ((size_t)(((gt * 32 + chunk) * 8 + nt) * 4 + ktl) * 64 + half * 16 + col) * 8;
  *(uint4*)(WhS + off) = u;
}

// ---- swizzle-convert W_dec fp32 [512][4096] -> WdS B-image bf16 ----
__global__ __launch_bounds__(512) void cvt_wdec_kernel(const float* __restrict__ W,
                                                       uint16_t* __restrict__ WdS) {
  const int idx = blockIdx.x * 512 + threadIdx.x;  // 256K threads
  const int p = idx >> 9;
  const int k0 = (idx & 511) << 3;
  const float4 x = *(const float4*)(W + (size_t)p * kNG + k0);
  const float4 y = *(const float4*)(W + (size_t)p * kNG + k0 + 4);
  uint4 u;
  u.x = (uint32_t)f2bf(x.x) | ((uint32_t)f2bf(x.y) << 16);
  u.y = (uint32_t)f2bf(x.z) | ((uint32_t)f2bf(x.w) << 16);
  u.z = (uint32_t)f2bf(y.x) | ((uint32_t)f2bf(y.y) << 16);
  u.w = (uint32_t)f2bf(y.z) | ((uint32_t)f2bf(y.w) << 16);
  const int pt = p >> 7, c = p & 127;
  const int nt = c >> 4, col = c & 15;
  const int chunk = k0 >> 7, ktl = (k0 >> 5) & 3, half = (k0 >> 3) & 3;
  const size_t off = ((size_t)(((pt * 32 + chunk) * 8 + nt) * 4 + ktl) * 64 + half * 16 + col) * 8;
  *(uint4*)(WdS + off) = u;
}

// ---- encoder: H0S = A-image of p0 @ Wenc^T (bf16) ----
__global__ __launch_bounds__(512, 2) void enc_kernel(const float* __restrict__ p0,
                                                     const float* __restrict__ Wenc,
                                                     uint16_t* __restrict__ H0S) {
  __shared__ alignas(16) uint16_t Wlds[16 * 64 * 8];
  const int tid = threadIdx.x;
  const int g0 = blockIdx.x * 16;
  for (int f = tid; f < 16 * 64; f += 512) {
    const int kt = f >> 6, fl = f & 63;
    const int g = g0 + (fl & 15);
    const int k = kt * 32 + ((fl >> 4) << 3);
    const float* s = Wenc + (size_t)g * kNP + k;
    uint16_t* d = Wlds + f * 8;
#pragma unroll
    for (int j = 0; j < 8; j++) d[j] = f2bf(s[j]);
  }
  __syncthreads();
  const int wave = tid >> 6;
  const int lane = tid & 63;
  const int mrow = wave * 16 + (lane & 15);
  const float* arow = p0 + (size_t)mrow * kNP + ((lane >> 4) << 3);
  f32x4 acc = {0.f, 0.f, 0.f, 0.f};
#pragma unroll
  for (int kt = 0; kt < 16; kt++) {
    const float* ap = arow + kt * 32;
    bf16x8 a;
#pragma unroll
    for (int j = 0; j < 8; j++) a[j] = (short)f2bf(ap[j]);
    bf16x8 b = *(const bf16x8*)(Wlds + (kt * 64 + lane) * 8);
    acc = __builtin_amdgcn_mfma_f32_16x16x32_bf16(a, b, acc, 0, 0, 0);
  }
  const int gcol = g0 + (lane & 15);
  const int rbase = wave * 16 + ((lane >> 4) << 2);
#pragma unroll
  for (int r = 0; r < 4; r++) {
    H0S[a_img_off(rbase + r, gcol)] = f2bf(acc[r]);
  }
}

// ---- persistent RNN loop: wave-autonomous flag sync, no t-loop barriers ----
__global__ __launch_bounds__(512, 2) void rnn_loop_kernel(const uint16_t* __restrict__ WhS,
                                                          const uint16_t* __restrict__ H0S,
                                                          uint16_t* __restrict__ Gsw,
                                                          float* __restrict__ Part,
                                                          const float* __restrict__ v,
                                                          const float* __restrict__ Wih,
                                                          int* __restrict__ flags) {
  extern __shared__ uint16_t wlds[];  // 131072 B
  const int tid = threadIdx.x;
  const int wave = tid >> 6, lane = tid & 63;
  const int bid = blockIdx.x;
  const int xcd = bid & 7;                 // dispatch round-robin heuristic (perf-only)
  const int gt = xcd * 4 + (bid >> 6);     // all 8 ks-blocks of gt on one XCD
  const int ks = (bid >> 3) & 7;
  const int mg = wave >> 1, ng = wave & 1;

  int* pcnt = flags;         // [gt*4+mg] stride 8 (32B): 16 adds/step
  int* hcnt = flags + 1024;  // [gt] stride 32 (128B): 64 adds/step

  // one-time: W tile (row gt, chunks ks*4..+3) -> LDS, linear copy
  {
    const uint16_t* src = WhS + ((size_t)gt << 19) + ((size_t)(ks * 4) << 14);
#pragma unroll
    for (int i = 0; i < 16; i++) {
      const int j = wave * 16 + i;
      gl2lds16(src + (j << 9) + (lane << 3), (void*)(wlds + (j << 9)));
    }
  }
  __syncthreads();  // only barrier in the kernel (W-residency)

  // reduce-phase coords: wave w handles rows ks*16 + {2w, 2w+1}; 4 g per thread
  const int rbred = ks * 16 + (tid >> 5);  // batch row
  const int gl = (tid & 31) << 2;          // local g 0..124
  const int gg = gt * 128 + gl;            // global g
  float* myPart = Part + (((size_t)(gt * 8 + ks)) << 14);

  // loop-invariant Wih rows for this thread's 4 g (hoisted out of t-loop)
  const float4 w0 = *(const float4*)(Wih + gg * 2);
  const float4 w1 = *(const float4*)(Wih + gg * 2 + 4);

  for (int t = 0; t < kT; t++) {
    // ---- per-wave wait: RAW on h chunks ks*4..+3; WAR on own chunk gt ----
    if (t > 0) {
      const int target = 64 * t;
      if (lane < 5) {
        int* f = (lane < 4) ? (hcnt + ((ks * 4 + lane) << 5)) : (hcnt + (gt << 5));
        while (__hip_atomic_load(f, __ATOMIC_RELAXED, __HIP_MEMORY_SCOPE_AGENT) < target)
          __builtin_amdgcn_s_sleep(1);
      }
      __builtin_amdgcn_fence(__ATOMIC_ACQUIRE, "workgroup");  // compiler order; no cache op
    }

    // prefetch v(t) for the reduce phase (latency hides under mm)
    const float v0 = v[(rbred * kT + t) * 2 + 0];
    const float v1 = v[(rbred * kT + t) * 2 + 1];

    const uint16_t* Aimg = (t == 0) ? H0S : (Gsw + (((size_t)(t - 1)) << 19));
    f32x4 acc[2][4];
#pragma unroll
    for (int i = 0; i < 2; i++)
#pragma unroll
      for (int j = 0; j < 4; j++) acc[i][j] = (f32x4){0.f, 0.f, 0.f, 0.f};

#pragma unroll
    for (int kc = 0; kc < 4; kc++) {
      const uint16_t* Ac = Aimg + ((size_t)(ks * 4 + kc) << 14);
      bf16x8 a[2][4];
#pragma unroll
      for (int mi = 0; mi < 2; mi++)
#pragma unroll
        for (int ktl = 0; ktl < 4; ktl++)
          a[mi][ktl] = *(const bf16x8*)(Ac + ((((mg * 2 + mi) * 4 + ktl) * 64 + lane) << 3));
#pragma unroll
      for (int ktl = 0; ktl < 4; ktl++) {
#pragma unroll
        for (int nt = 0; nt < 4; nt++) {
          bf16x8 b = *(const bf16x8*)(wlds + (kc << 14) +
                                      ((((ng * 4 + nt) * 4 + ktl) * 64 + lane) << 3));
          acc[0][nt] = __builtin_amdgcn_mfma_f32_16x16x32_bf16(a[0][ktl], b, acc[0][nt], 0, 0, 0);
          acc[1][nt] = __builtin_amdgcn_mfma_f32_16x16x32_bf16(a[1][ktl], b, acc[1][nt], 0, 0, 0);
        }
      }
    }
    // Part write: normal stores (rows mg*32..+31, cols ng*64..+63 of myPart)
    {
      const int gcol0 = (ng << 6);
      const int rbase = (mg << 5) + ((lane >> 4) << 2);
#pragma unroll
      for (int mi = 0; mi < 2; mi++)
#pragma unroll
        for (int nt = 0; nt < 4; nt++)
#pragma unroll
          for (int r = 0; r < 4; r++) {
            const int b = rbase + (mi << 4) + r;
            const int g = gcol0 + (nt << 4) + (lane & 15);
            myPart[(b << 7) + g] = acc[mi][nt][r];
          }
    }
    asm volatile("s_waitcnt vmcnt(0)" ::: "memory");  // this wave's Part committed
    if (lane == 0)  // publish this wave's slice
      __hip_atomic_fetch_add(pcnt + (((gt << 2) + mg) << 3), 1, __ATOMIC_RELAXED,
                             __HIP_MEMORY_SCOPE_AGENT);

    // ---- per-wave wait: the 16 producer waves covering rows ks*16..+15 ----
    {
      const int tgt = 16 * (t + 1);
      if (lane == 0) {
        int* f = pcnt + (((gt << 2) + (ks >> 1)) << 3);
        while (__hip_atomic_load(f, __ATOMIC_RELAXED, __HIP_MEMORY_SCOPE_AGENT) < tgt)
          __builtin_amdgcn_s_sleep(1);
      }
      __builtin_amdgcn_fence(__ATOMIC_ACQUIRE, "workgroup");  // compiler order only
    }

    // reduce rows {2w,2w+1} over 8 slices + vin + tanh -> Gsw[t] A-image.
    // Part reads: sc0 probe (bypass stale L1; coherent via L2/LLC probe path).
    {
      const float* pb = Part + (((size_t)(gt * 8)) << 14) + (rbred << 7) + gl;
      f32x4 pv[8];
#pragma unroll
      for (int j = 0; j < 8; j++) {
        asm volatile("global_load_dwordx4 %0, %1, off sc0"
                     : "=v"(pv[j])
                     : "v"(pb + ((size_t)j << 14))
                     : "memory");
      }
      asm volatile("s_waitcnt vmcnt(0)" ::: "memory");
      __builtin_amdgcn_sched_barrier(0);  // rule #18: keep VALU below the waitcnt
      float s0 = 0.f, s1 = 0.f, s2 = 0.f, s3 = 0.f;
#pragma unroll
      for (int j = 0; j < 8; j++) {
        s0 += pv[j][0]; s1 += pv[j][1]; s2 += pv[j][2]; s3 += pv[j][3];
      }
      const uint16_t h0 = f2bf(fast_tanh(s0 + v0 * w0.x + v1 * w0.y));
      const uint16_t h1 = f2bf(fast_tanh(s1 + v0 * w0.z + v1 * w0.w));
      const uint16_t h2 = f2bf(fast_tanh(s2 + v0 * w1.x + v1 * w1.y));
      const uint16_t h3 = f2bf(fast_tanh(s3 + v0 * w1.z + v1 * w1.w));
      const uint32_t lo = (uint32_t)h0 | ((uint32_t)h1 << 16);
      const uint32_t hi = (uint32_t)h2 | ((uint32_t)h3 << 16);
      const unsigned long long uval = ((unsigned long long)hi << 32) | lo;
      uint16_t* Gt = Gsw + (((size_t)t) << 19);
      // h publish: atomic swap executes at the LLC (agent coherence point)
      __hip_atomic_exchange((unsigned long long*)(Gt + a_img_off(rbred, gg)), uval,
                            __ATOMIC_RELAXED, __HIP_MEMORY_SCOPE_AGENT);
    }
    asm volatile("s_waitcnt vmcnt(0)" ::: "memory");  // this wave's h swaps done
    if (lane == 0)  // publish this wave's 2 reduced rows of chunk gt
      __hip_atomic_fetch_add(hcnt + (gt << 5), 1, __ATOMIC_RELAXED,
                             __HIP_MEMORY_SCOPE_AGENT);
  }
}

// ---- fallback step kernels (used only if cooperative launch is refused) ----
__global__ __launch_bounds__(512, 4) void stepmm_kernel(const uint16_t* __restrict__ Asrc,
                                                        const uint16_t* __restrict__ WhS,
                                                        float* __restrict__ Part) {
  __shared__ alignas(16) uint16_t lds[32768];
  const int tid = threadIdx.x;
  const int wave = tid >> 6, lane = tid & 63;
  const int gt = blockIdx.x >> 3, ks = blockIdx.x & 7;
  const int mg = wave >> 1, ng = wave & 1;
  const uint16_t* Wbase = WhS + ((size_t)gt << 19);
  f32x4 acc[2][4];
#pragma unroll
  for (int i = 0; i < 2; i++)
#pragma unroll
    for (int j = 0; j < 4; j++) acc[i][j] = (f32x4){0.f, 0.f, 0.f, 0.f};

  for (int kc = 0; kc < 4; kc++) {
    const int chunk = ks * 4 + kc;
    const uint16_t* Ac = Asrc + ((size_t)chunk << 14);
    const uint16_t* Bc = Wbase + ((size_t)chunk << 14);
#pragma unroll
    for (int i = 0; i < 8; i++) {
      const int j = wave * 8 + i;
      const uint16_t* s = (j < 32) ? (Ac + (j << 9)) : (Bc + ((j - 32) << 9));
      gl2lds16(s + (lane << 3), (void*)(lds + (j << 9)));
    }
    __syncthreads();
    const uint16_t* lA = lds;
    const uint16_t* lB = lds + 16384;
#pragma unroll
    for (int ktl = 0; ktl < 4; ktl++) {
      bf16x8 a0 = *(const bf16x8*)(lA + ((((mg * 2 + 0) * 4 + ktl) * 64 + lane) << 3));
      bf16x8 a1 = *(const bf16x8*)(lA + ((((mg * 2 + 1) * 4 + ktl) * 64 + lane) << 3));
#pragma unroll
      for (int nt = 0; nt < 4; nt++) {
        bf16x8 b = *(const bf16x8*)(lB + ((((ng * 4 + nt) * 4 + ktl) * 64 + lane) << 3));
        acc[0][nt] = __builtin_amdgcn_mfma_f32_16x16x32_bf16(a0, b, acc[0][nt], 0, 0, 0);
        acc[1][nt] = __builtin_amdgcn_mfma_f32_16x16x32_bf16(a1, b, acc[1][nt], 0, 0, 0);
      }
    }
    __syncthreads();
  }
  const int g0 = (gt << 7) + (ng << 6);
  const int rb = (mg << 5) + ((lane >> 4) << 2);
#pragma unroll
  for (int mi = 0; mi < 2; mi++)
#pragma unroll
    for (int nt = 0; nt < 4; nt++)
#pragma unroll
      for (int r = 0; r < 4; r++) {
        const int b = rb + (mi << 4) + r;
        const int g = g0 + (nt << 4) + (lane & 15);
        Part[(((size_t)(ks * 128 + b)) << 12) + g] = acc[mi][nt][r];
      }
}

__global__ __launch_bounds__(256) void steptanh_kernel(const float* __restrict__ Part,
                                                       const float* __restrict__ v,
                                                       const float* __restrict__ Wih,
                                                       uint16_t* __restrict__ Gt, int t) {
  const int tg = blockIdx.x * 256 + threadIdx.x;
  const int b = tg >> 9;
  const int g0 = (tg & 511) << 3;
  float s[8];
#pragma unroll
  for (int j = 0; j < 8; j++) s[j] = 0.f;
#pragma unroll
  for (int ks = 0; ks < 8; ks++) {
    const float4* p = (const float4*)(Part + (((size_t)(ks * 128 + b)) << 12) + g0);
    const float4 x = p[0], y = p[1];
    s[0] += x.x; s[1] += x.y; s[2] += x.z; s[3] += x.w;
    s[4] += y.x; s[5] += y.y; s[6] += y.z; s[7] += y.w;
  }
  const float v0 = v[(b * kT + t) * 2 + 0];
  const float v1 = v[(b * kT + t) * 2 + 1];
  uint16_t h[8];
#pragma unroll
  for (int j = 0; j < 8; j++) {
    const int g = g0 + j;
    const float pre = s[j] + v0 * Wih[g * 2 + 0] + v1 * Wih[g * 2 + 1];
    h[j] = f2bf(fast_tanh(pre));
  }
  uint4 u;
  u.x = (uint32_t)h[0] | ((uint32_t)h[1] << 16);
  u.y = (uint32_t)h[2] | ((uint32_t)h[3] << 16);
  u.z = (uint32_t)h[4] | ((uint32_t)h[5] << 16);
  u.w = (uint32_t)h[6] | ((uint32_t)h[7] << 16);
  const size_t off = ((size_t)(((g0 >> 7) * 8 + (b >> 4)) * 4 + ((g0 >> 5) & 3)) * 64 +
                      ((g0 >> 3) & 3) * 16 + (b & 15)) * 8;
  *(uint4*)(Gt + off) = u;
}

// ---- decoder: out[b,t,p] = Gsw[t] @ WdS[pt] + bias. block=(t, pt), 32 k-chunks ----
__global__ __launch_bounds__(512, 4) void dec_kernel(const uint16_t* __restrict__ Gsw,
                                                     const uint16_t* __restrict__ WdS,
                                                     const float* __restrict__ bd,
                                                     float* __restrict__ out) {
  __shared__ alignas(16) uint16_t lds[32768];
  const int tid = threadIdx.x;
  const int wave = tid >> 6, lane = tid & 63;
  const int t = blockIdx.x >> 2, pt = blockIdx.x & 3;
  const int mg = wave >> 1, ng = wave & 1;
  const uint16_t* Abase = Gsw + (size_t)t * 524288;
  const uint16_t* Bbase = WdS + (size_t)pt * 524288;
  f32x4 acc[2][4];
#pragma unroll
  for (int i = 0; i < 2; i++)
#pragma unroll
    for (int j = 0; j < 4; j++) acc[i][j] = (f32x4){0.f, 0.f, 0.f, 0.f};

  for (int chunk = 0; chunk < 32; chunk++) {
    const uint16_t* Ac = Abase + ((size_t)chunk << 14);
    const uint16_t* Bc = Bbase + ((size_t)chunk << 14);
#pragma unroll
    for (int i = 0; i < 8; i++) {
      const int j = wave * 8 + i;
      const uint16_t* s = (j < 32) ? (Ac + (j << 9)) : (Bc + ((j - 32) << 9));
      gl2lds16(s + (lane << 3), (void*)(lds + (j << 9)));
    }
    __syncthreads();
    const uint16_t* lA = lds;
    const uint16_t* lB = lds + 16384;
#pragma unroll
    for (int ktl = 0; ktl < 4; ktl++) {
      bf16x8 a0 = *(const bf16x8*)(lA + ((((mg * 2 + 0) * 4 + ktl) * 64 + lane) << 3));
      bf16x8 a1 = *(const bf16x8*)(lA + ((((mg * 2 + 1) * 4 + ktl) * 64 + lane) << 3));
#pragma unroll
      for (int nt = 0; nt < 4; nt++) {
        bf16x8 b = *(const bf16x8*)(lB + ((((ng * 4 + nt) * 4 + ktl) * 64 + lane) << 3));
        acc[0][nt] = __builtin_amdgcn_mfma_f32_16x16x32_bf16(a0, b, acc[0][nt], 0, 0, 0);
        acc[1][nt] = __builtin_amdgcn_mfma_f32_16x16x32_bf16(a1, b, acc[1][nt], 0, 0, 0);
      }
    }
    __syncthreads();
  }
  const int p0c = (pt << 7) + (ng << 6);
  const int rb = (mg << 5) + ((lane >> 4) << 2);
#pragma unroll
  for (int mi = 0; mi < 2; mi++)
#pragma unroll
    for (int nt = 0; nt < 4; nt++) {
      const int p = p0c + (nt << 4) + (lane & 15);
      const float bias = bd[p];
#pragma unroll
      for (int r = 0; r < 4; r++) {
        const int b = rb + (mi << 4) + r;
        out[((size_t)b * kT + t) * kNP + p] = acc[mi][nt][r] + bias;
      }
    }
}

extern "C" void kernel_launch(void* const* d_in, const int* in_sizes, int n_in,
                              void* d_out, int out_size, void* d_ws, size_t ws_size,
                              hipStream_t stream) {
  const float* v    = (const float*)d_in[0];
  const float* p0   = (const float*)d_in[1];
  const float* Wenc = (const float*)d_in[2];
  const float* Wih  = (const float*)d_in[3];
  const float* Whh  = (const float*)d_in[4];
  const float* Wdec = (const float*)d_in[5];
  const float* bdec = (const float*)d_in[6];
  float* out = (float*)d_out;

  uint8_t* ws = (uint8_t*)d_ws;
  uint16_t* WhS = (uint16_t*)(ws);
  uint16_t* WdS = (uint16_t*)(ws + 33554432);
  uint16_t* H0S = (uint16_t*)(ws + 37748736);
  uint16_t* Gsw = (uint16_t*)(ws + 38797312);
  float*    Part = (float*)(ws + 143654912);
  int*      flags = (int*)(ws + 160432128);

  cvt_whh_kernel<<<4096, 512, 0, stream>>>(Whh, WhS, flags);
  cvt_wdec_kernel<<<512, 512, 0, stream>>>(Wdec, WdS);
  enc_kernel<<<256, 512, 0, stream>>>(p0, Wenc, H0S);

  // persistent flag-synced RNN loop (cooperative launch for residency guarantee)
  const uint16_t* WhS_c = WhS;
  const uint16_t* H0S_c = H0S;
  void* args[7] = {(void*)&WhS_c, (void*)&H0S_c, (void*)&Gsw, (void*)&Part,
                   (void*)&v, (void*)&Wih, (void*)&flags};
  hipError_t e = hipLaunchCooperativeKernel(rnn_loop_kernel, dim3(256), dim3(512), args,
                                            (unsigned int)131072, stream);
  if (e != hipSuccess) {
    // fallback: per-step launches (round-1 path, ~1.96 ms class)
    (void)hipGetLastError();
    for (int t = 0; t < kT; t++) {
      const uint16_t* Asrc = (t == 0) ? H0S : (Gsw + (size_t)(t - 1) * 524288);
      stepmm_kernel<<<256, 512, 0, stream>>>(Asrc, WhS, Part);
      steptanh_kernel<<<256, 256, 0, stream>>>(Part, v, Wih, Gsw + (size_t)t * 524288, t);
    }
  }

  dec_kernel<<<400, 512, 0, stream>>>(Gsw, WdS, bdec, out);
}

// Round 8
// 1351.601 us; speedup vs baseline: 2.9458x; 2.9458x over previous
//
// RNN_79577154060490 — round 9: round-6 verified base + LLC stamp flags +
// L1-only invalidate with NORMAL (L2-hit) Part reads.
// h0=p0@W_enc^T; 100x h=tanh(v@W_ih^T+h@W_hh^T); out = g@W_dec^T + b
//
// Round-7 (per-wave flags): REGRESSION 3430us — 8x LLC RMW+spinners. Reverted.
// Round-8 (pflag plain-store/sc0-poll): no result; correctness depended on the
// undefined block->XCD mapping (possible hang). Reverted to LLC atomics.
// Round-6 counter re-read: WRITE_SIZE 15MB/step == Part size -> the sc0 Part
// reads force dirty lines OUT of L2 (probe/bypass), so Part round-trips
// L2->MALL->L2 every step. Only real hazard for normal loads is the consumer's
// stale L1 (same addresses every step).
// Round-9 changes:
//  * flags -> single-writer STAMPS at LLC: pstamp/hstamp[gt*8+ks]=t+1 via
//    __hip_atomic_exchange AGENT (proven primitive); polls via atomic loads on
//    independent words (no RMW serialization). Mapping-independent.
//  * Part reads: `buffer_inv sc0` (L1-only invalidate) after the rendezvous,
//    then PLAIN dwordx4 loads -> hit the XCD-shared L2 where producers' normal
//    stores live. No L2 writeback, no MALL round trip.
//  * keep: h publish via agent atomic-exchange (cross-XCD, verified); A plain
//    cached; W_hh LDS-resident; Wih hoist; v(t) prefetch.
//
// ws layout (bytes):
//   [0,         33554432)   WhS  bf16 [gt32][chunk32][nt8][ktl4][64][8]
//   [33554432,  37748736)   WdS  bf16 [pt4][chunk32][nt8][ktl4][64][8]
//   [37748736,  38797312)   H0S  bf16 A-image (1MB)
//   [38797312, 143654912)   Gsw  bf16 [t100] A-images (100MB)
//   [143654912,160432128)   Part fp32 [gt32][ks8][128][128] (16MB)
//   [160432128,160440320)   flags int[2048]: pstamp[256] @0; hstamp[256] @+256

#include <hip/hip_runtime.h>
#include <stdint.h>

namespace {
constexpr int kT = 100;
constexpr int kNG = 4096;
constexpr int kNP = 512;

__device__ __forceinline__ uint16_t f2bf(float f) {
  uint32_t u = __float_as_uint(f);
  u += 0x7FFFu + ((u >> 16) & 1u);
  return (uint16_t)(u >> 16);
}

__device__ __forceinline__ float fast_tanh(float x) {
  float xc = fminf(fmaxf(x, -15.f), 15.f);
  float e = __expf(2.f * xc);
  return (e - 1.f) / (e + 1.f);
}

__device__ __forceinline__ void gl2lds16(const void* g, void* l) {
  __builtin_amdgcn_global_load_lds((const __attribute__((address_space(1))) unsigned int*)g,
                                   (__attribute__((address_space(3))) unsigned int*)l, 16, 0, 0);
}

// fragment-image element offsets (within one tensor)
__device__ __forceinline__ size_t a_img_off(int b, int g) {  // g = k index
  return ((size_t)(((g >> 7) * 8 + (b >> 4)) * 4 + ((g >> 5) & 3)) * 64 +
          ((g >> 3) & 3) * 16 + (b & 15)) * 8 + (g & 7);
}
}  // namespace

typedef short bf16x8 __attribute__((ext_vector_type(8)));
typedef float f32x4 __attribute__((ext_vector_type(4)));

// ---- swizzle-convert W_hh fp32 [4096][4096] -> WhS B-image bf16 (+flag zero) ----
__global__ __launch_bounds__(512) void cvt_whh_kernel(const float* __restrict__ W,
                                                      uint16_t* __restrict__ WhS,
                                                      int* __restrict__ flags) {
  if (blockIdx.x == 4095) {
    for (int i = threadIdx.x; i < 2048; i += 512) flags[i] = 0;
  }
  const int idx = blockIdx.x * 512 + threadIdx.x;  // 2M threads
  const int g = idx >> 9;
  const int k0 = (idx & 511) << 3;
  const float4 x = *(const float4*)(W + (size_t)g * kNG + k0);
  const float4 y = *(const float4*)(W + (size_t)g * kNG + k0 + 4);
  uint4 u;
  u.x = (uint32_t)f2bf(x.x) | ((uint32_t)f2bf(x.y) << 16);
  u.y = (uint32_t)f2bf(x.z) | ((uint32_t)f2bf(x.w) << 16);
  u.z = (uint32_t)f2bf(y.x) | ((uint32_t)f2bf(y.y) << 16);
  u.w = (uint32_t)f2bf(y.z) | ((uint32_t)f2bf(y.w) << 16);
  const int gt = g >> 7, c = g & 127;
  const int nt = c >> 4, col = c & 15;
  const int chunk = k0 >> 7, ktl = (k0 >> 5) & 3, half = (k0 >> 3) & 3;
  const size_t off = ((size_t)(((gt * 32 + chunk) * 8 + nt) * 4 + ktl) * 64 + half * 16 + col) * 8;
  *(uint4*)(WhS + off) = u;
}

// ---- swizzle-convert W_dec fp32 [512][4096] -> WdS B-image bf16 ----
__global__ __launch_bounds__(512) void cvt_wdec_kernel(const float* __restrict__ W,
                                                       uint16_t* __restrict__ WdS) {
  const int idx = blockIdx.x * 512 + threadIdx.x;  // 256K threads
  const int p = idx >> 9;
  const int k0 = (idx & 511) << 3;
  const float4 x = *(const float4*)(W + (size_t)p * kNG + k0);
  const float4 y = *(const float4*)(W + (size_t)p * kNG + k0 + 4);
  uint4 u;
  u.x = (uint32_t)f2bf(x.x) | ((uint32_t)f2bf(x.y) << 16);
  u.y = (uint32_t)f2bf(x.z) | ((uint32_t)f2bf(x.w) << 16);
  u.z = (uint32_t)f2bf(y.x) | ((uint32_t)f2bf(y.y) << 16);
  u.w = (uint32_t)f2bf(y.z) | ((uint32_t)f2bf(y.w) << 16);
  const int pt = p >> 7, c = p & 127;
  const int nt = c >> 4, col = c & 15;
  const int chunk = k0 >> 7, ktl = (k0 >> 5) & 3, half = (k0 >> 3) & 3;
  const size_t off = ((size_t)(((pt * 32 + chunk) * 8 + nt) * 4 + ktl) * 64 + half * 16 + col) * 8;
  *(uint4*)(WdS + off) = u;
}

// ---- encoder: H0S = A-image of p0 @ Wenc^T (bf16) ----
__global__ __launch_bounds__(512, 2) void enc_kernel(const float* __restrict__ p0,
                                                     const float* __restrict__ Wenc,
                                                     uint16_t* __restrict__ H0S) {
  __shared__ alignas(16) uint16_t Wlds[16 * 64 * 8];
  const int tid = threadIdx.x;
  const int g0 = blockIdx.x * 16;
  for (int f = tid; f < 16 * 64; f += 512) {
    const int kt = f >> 6, fl = f & 63;
    const int g = g0 + (fl & 15);
    const int k = kt * 32 + ((fl >> 4) << 3);
    const float* s = Wenc + (size_t)g * kNP + k;
    uint16_t* d = Wlds + f * 8;
#pragma unroll
    for (int j = 0; j < 8; j++) d[j] = f2bf(s[j]);
  }
  __syncthreads();
  const int wave = tid >> 6;
  const int lane = tid & 63;
  const int mrow = wave * 16 + (lane & 15);
  const float* arow = p0 + (size_t)mrow * kNP + ((lane >> 4) << 3);
  f32x4 acc = {0.f, 0.f, 0.f, 0.f};
#pragma unroll
  for (int kt = 0; kt < 16; kt++) {
    const float* ap = arow + kt * 32;
    bf16x8 a;
#pragma unroll
    for (int j = 0; j < 8; j++) a[j] = (short)f2bf(ap[j]);
    bf16x8 b = *(const bf16x8*)(Wlds + (kt * 64 + lane) * 8);
    acc = __builtin_amdgcn_mfma_f32_16x16x32_bf16(a, b, acc, 0, 0, 0);
  }
  const int gcol = g0 + (lane & 15);
  const int rbase = wave * 16 + ((lane >> 4) << 2);
#pragma unroll
  for (int r = 0; r < 4; r++) {
    H0S[a_img_off(rbase + r, gcol)] = f2bf(acc[r]);
  }
}

// ---- persistent RNN loop: block-synchronous, LLC stamp flags, L1-inv reads ----
__global__ __launch_bounds__(512, 2) void rnn_loop_kernel(const uint16_t* __restrict__ WhS,
                                                          const uint16_t* __restrict__ H0S,
                                                          uint16_t* __restrict__ Gsw,
                                                          float* __restrict__ Part,
                                                          const float* __restrict__ v,
                                                          const float* __restrict__ Wih,
                                                          int* __restrict__ flags) {
  extern __shared__ uint16_t wlds[];  // 131072 B
  const int tid = threadIdx.x;
  const int wave = tid >> 6, lane = tid & 63;
  const int bid = blockIdx.x;
  const int xcd = bid & 7;                 // dispatch round-robin heuristic (perf-only)
  const int gt = xcd * 4 + (bid >> 6);     // all 8 ks-blocks of gt on one XCD
  const int ks = (bid >> 3) & 7;
  const int mg = wave >> 1, ng = wave & 1;

  int* pstamp = flags;        // [gt*8+ks] = t+1 when Part slice ready (LLC)
  int* hstamp = flags + 256;  // [gt*8+ks] = t+1 when h rows reduced   (LLC)

  // one-time: W tile (row gt, chunks ks*4..+3) -> LDS, linear copy
  {
    const uint16_t* src = WhS + ((size_t)gt << 19) + ((size_t)(ks * 4) << 14);
#pragma unroll
    for (int i = 0; i < 16; i++) {
      const int j = wave * 16 + i;
      gl2lds16(src + (j << 9) + (lane << 3), (void*)(wlds + (j << 9)));
    }
  }
  __syncthreads();

  // reduce-phase coords: 16 rows x 128 g per block, 4 g per thread
  const int rbred = ks * 16 + (tid >> 5);  // batch row
  const int gl = (tid & 31) << 2;          // local g 0..124
  const int gg = gt * 128 + gl;            // global g
  float* myPart = Part + (((size_t)(gt * 8 + ks)) << 14);

  // loop-invariant Wih rows for this thread's 4 g (hoisted out of t-loop)
  const float4 w0 = *(const float4*)(Wih + gg * 2);
  const float4 w1 = *(const float4*)(Wih + gg * 2 + 4);

  for (int t = 0; t < kT; t++) {
    // ---- h-wait: RAW on chunks ks*4..+3 (8 writer blocks each = 32 words) +
    //              WAR on my Part's 8 reader blocks (hstamp[gt*8+*]) ----
    if (t > 0) {
      if (tid < 40) {
        const int idx = (tid < 32) ? ((ks * 4 + (tid >> 3)) * 8 + (tid & 7))
                                   : (gt * 8 + (tid - 32));
        int* f = hstamp + idx;
        while (__hip_atomic_load(f, __ATOMIC_RELAXED, __HIP_MEMORY_SCOPE_AGENT) < t)
          __builtin_amdgcn_s_sleep(1);
      }
      __builtin_amdgcn_fence(__ATOMIC_ACQUIRE, "workgroup");  // compiler order; no cache op
      __syncthreads();
    }

    // prefetch v(t) for the reduce phase (latency hides under mm)
    const float v0 = v[(rbred * kT + t) * 2 + 0];
    const float v1 = v[(rbred * kT + t) * 2 + 1];

    const uint16_t* Aimg = (t == 0) ? H0S : (Gsw + (((size_t)(t - 1)) << 19));
    f32x4 acc[2][4];
#pragma unroll
    for (int i = 0; i < 2; i++)
#pragma unroll
      for (int j = 0; j < 4; j++) acc[i][j] = (f32x4){0.f, 0.f, 0.f, 0.f};

#pragma unroll
    for (int kc = 0; kc < 4; kc++) {
      const uint16_t* Ac = Aimg + ((size_t)(ks * 4 + kc) << 14);
      bf16x8 a[2][4];
#pragma unroll
      for (int mi = 0; mi < 2; mi++)
#pragma unroll
        for (int ktl = 0; ktl < 4; ktl++)
          a[mi][ktl] = *(const bf16x8*)(Ac + ((((mg * 2 + mi) * 4 + ktl) * 64 + lane) << 3));
#pragma unroll
      for (int ktl = 0; ktl < 4; ktl++) {
#pragma unroll
        for (int nt = 0; nt < 4; nt++) {
          bf16x8 b = *(const bf16x8*)(wlds + (kc << 14) +
                                      ((((ng * 4 + nt) * 4 + ktl) * 64 + lane) << 3));
          acc[0][nt] = __builtin_amdgcn_mfma_f32_16x16x32_bf16(a[0][ktl], b, acc[0][nt], 0, 0, 0);
          acc[1][nt] = __builtin_amdgcn_mfma_f32_16x16x32_bf16(a[1][ktl], b, acc[1][nt], 0, 0, 0);
        }
      }
    }
    // Part write: normal stores -> XCD-shared L2 (stays there; no EA trip)
    {
      const int gcol0 = (ng << 6);
      const int rbase = (mg << 5) + ((lane >> 4) << 2);
#pragma unroll
      for (int mi = 0; mi < 2; mi++)
#pragma unroll
        for (int nt = 0; nt < 4; nt++)
#pragma unroll
          for (int r = 0; r < 4; r++) {
            const int b = rbase + (mi << 4) + r;
            const int g = gcol0 + (nt << 4) + (lane & 15);
            myPart[(b << 7) + g] = acc[mi][nt][r];
          }
    }
    asm volatile("s_waitcnt vmcnt(0)" ::: "memory");  // this wave's Part in L2
    __syncthreads();                                   // all waves' Part in L2
    if (tid == 0)  // stamp Part-ready (single-writer word at the LLC)
      __hip_atomic_exchange(pstamp + gt * 8 + ks, t + 1, __ATOMIC_RELAXED,
                            __HIP_MEMORY_SCOPE_AGENT);
    if (tid < 8) {  // wait for all 8 slices of this gt
      while (__hip_atomic_load(pstamp + gt * 8 + tid, __ATOMIC_RELAXED,
                               __HIP_MEMORY_SCOPE_AGENT) < t + 1)
        __builtin_amdgcn_s_sleep(1);
    }
    __builtin_amdgcn_fence(__ATOMIC_ACQUIRE, "workgroup");  // compiler order only
    __syncthreads();

    // L1-only invalidate: Part addresses are reused each step, so this CU's L1
    // may hold stale copies. Dropping L1 makes the PLAIN loads below read the
    // XCD-shared L2 (where producers' stores live) without forcing writebacks.
    asm volatile("buffer_inv sc0\n\ts_waitcnt vmcnt(0)" ::: "memory");

    // reduce rows [16ks..+16) over 8 slices + vin + tanh -> Gsw[t] A-image.
    {
      const float* pb = Part + (((size_t)(gt * 8)) << 14) + (rbred << 7) + gl;
      f32x4 pv[8];
#pragma unroll
      for (int j = 0; j < 8; j++) pv[j] = *(const f32x4*)(pb + ((size_t)j << 14));
      float s0 = 0.f, s1 = 0.f, s2 = 0.f, s3 = 0.f;
#pragma unroll
      for (int j = 0; j < 8; j++) {
        s0 += pv[j][0]; s1 += pv[j][1]; s2 += pv[j][2]; s3 += pv[j][3];
      }
      const uint16_t h0 = f2bf(fast_tanh(s0 + v0 * w0.x + v1 * w0.y));
      const uint16_t h1 = f2bf(fast_tanh(s1 + v0 * w0.z + v1 * w0.w));
      const uint16_t h2 = f2bf(fast_tanh(s2 + v0 * w1.x + v1 * w1.y));
      const uint16_t h3 = f2bf(fast_tanh(s3 + v0 * w1.z + v1 * w1.w));
      const uint32_t lo = (uint32_t)h0 | ((uint32_t)h1 << 16);
      const uint32_t hi = (uint32_t)h2 | ((uint32_t)h3 << 16);
      const unsigned long long uval = ((unsigned long long)hi << 32) | lo;
      uint16_t* Gt = Gsw + (((size_t)t) << 19);
      // h publish: atomic swap executes at the LLC (agent coherence point) ->
      // cross-XCD readers fetch fresh data. (Verified rounds 6.)
      __hip_atomic_exchange((unsigned long long*)(Gt + a_img_off(rbred, gg)), uval,
                            __ATOMIC_RELAXED, __HIP_MEMORY_SCOPE_AGENT);
    }
    asm volatile("s_waitcnt vmcnt(0)" ::: "memory");  // this wave's h at LLC
    __syncthreads();                                   // whole block's h at LLC
    if (tid == 0)  // stamp h-ready (single-writer word at the LLC)
      __hip_atomic_exchange(hstamp + gt * 8 + ks, t + 1, __ATOMIC_RELAXED,
                            __HIP_MEMORY_SCOPE_AGENT);
  }
}

// ---- fallback step kernels (used only if cooperative launch is refused) ----
__global__ __launch_bounds__(512, 4) void stepmm_kernel(const uint16_t* __restrict__ Asrc,
                                                        const uint16_t* __restrict__ WhS,
                                                        float* __restrict__ Part) {
  __shared__ alignas(16) uint16_t lds[32768];
  const int tid = threadIdx.x;
  const int wave = tid >> 6, lane = tid & 63;
  const int gt = blockIdx.x >> 3, ks = blockIdx.x & 7;
  const int mg = wave >> 1, ng = wave & 1;
  const uint16_t* Wbase = WhS + ((size_t)gt << 19);
  f32x4 acc[2][4];
#pragma unroll
  for (int i = 0; i < 2; i++)
#pragma unroll
    for (int j = 0; j < 4; j++) acc[i][j] = (f32x4){0.f, 0.f, 0.f, 0.f};

  for (int kc = 0; kc < 4; kc++) {
    const int chunk = ks * 4 + kc;
    const uint16_t* Ac = Asrc + ((size_t)chunk << 14);
    const uint16_t* Bc = Wbase + ((size_t)chunk << 14);
#pragma unroll
    for (int i = 0; i < 8; i++) {
      const int j = wave * 8 + i;
      const uint16_t* s = (j < 32) ? (Ac + (j << 9)) : (Bc + ((j - 32) << 9));
      gl2lds16(s + (lane << 3), (void*)(lds + (j << 9)));
    }
    __syncthreads();
    const uint16_t* lA = lds;
    const uint16_t* lB = lds + 16384;
#pragma unroll
    for (int ktl = 0; ktl < 4; ktl++) {
      bf16x8 a0 = *(const bf16x8*)(lA + ((((mg * 2 + 0) * 4 + ktl) * 64 + lane) << 3));
      bf16x8 a1 = *(const bf16x8*)(lA + ((((mg * 2 + 1) * 4 + ktl) * 64 + lane) << 3));
#pragma unroll
      for (int nt = 0; nt < 4; nt++) {
        bf16x8 b = *(const bf16x8*)(lB + ((((ng * 4 + nt) * 4 + ktl) * 64 + lane) << 3));
        acc[0][nt] = __builtin_amdgcn_mfma_f32_16x16x32_bf16(a0, b, acc[0][nt], 0, 0, 0);
        acc[1][nt] = __builtin_amdgcn_mfma_f32_16x16x32_bf16(a1, b, acc[1][nt], 0, 0, 0);
      }
    }
    __syncthreads();
  }
  const int g0 = (gt << 7) + (ng << 6);
  const int rb = (mg << 5) + ((lane >> 4) << 2);
#pragma unroll
  for (int mi = 0; mi < 2; mi++)
#pragma unroll
    for (int nt = 0; nt < 4; nt++)
#pragma unroll
      for (int r = 0; r < 4; r++) {
        const int b = rb + (mi << 4) + r;
        const int g = g0 + (nt << 4) + (lane & 15);
        Part[(((size_t)(ks * 128 + b)) << 12) + g] = acc[mi][nt][r];
      }
}

__global__ __launch_bounds__(256) void steptanh_kernel(const float* __restrict__ Part,
                                                       const float* __restrict__ v,
                                                       const float* __restrict__ Wih,
                                                       uint16_t* __restrict__ Gt, int t) {
  const int tg = blockIdx.x * 256 + threadIdx.x;
  const int b = tg >> 9;
  const int g0 = (tg & 511) << 3;
  float s[8];
#pragma unroll
  for (int j = 0; j < 8; j++) s[j] = 0.f;
#pragma unroll
  for (int ks = 0; ks < 8; ks++) {
    const float4* p = (const float4*)(Part + (((size_t)(ks * 128 + b)) << 12) + g0);
    const float4 x = p[0], y = p[1];
    s[0] += x.x; s[1] += x.y; s[2] += x.z; s[3] += x.w;
    s[4] += y.x; s[5] += y.y; s[6] += y.z; s[7] += y.w;
  }
  const float v0 = v[(b * kT + t) * 2 + 0];
  const float v1 = v[(b * kT + t) * 2 + 1];
  uint16_t h[8];
#pragma unroll
  for (int j = 0; j < 8; j++) {
    const int g = g0 + j;
    const float pre = s[j] + v0 * Wih[g * 2 + 0] + v1 * Wih[g * 2 + 1];
    h[j] = f2bf(fast_tanh(pre));
  }
  uint4 u;
  u.x = (uint32_t)h[0] | ((uint32_t)h[1] << 16);
  u.y = (uint32_t)h[2] | ((uint32_t)h[3] << 16);
  u.z = (uint32_t)h[4] | ((uint32_t)h[5] << 16);
  u.w = (uint32_t)h[6] | ((uint32_t)h[7] << 16);
  const size_t off = ((size_t)(((g0 >> 7) * 8 + (b >> 4)) * 4 + ((g0 >> 5) & 3)) * 64 +
                      ((g0 >> 3) & 3) * 16 + (b & 15)) * 8;
  *(uint4*)(Gt + off) = u;
}

// ---- decoder: out[b,t,p] = Gsw[t] @ WdS[pt] + bias. block=(t, pt), 32 k-chunks ----
__global__ __launch_bounds__(512, 4) void dec_kernel(const uint16_t* __restrict__ Gsw,
                                                     const uint16_t* __restrict__ WdS,
                                                     const float* __restrict__ bd,
                                                     float* __restrict__ out) {
  __shared__ alignas(16) uint16_t lds[32768];
  const int tid = threadIdx.x;
  const int wave = tid >> 6, lane = tid & 63;
  const int t = blockIdx.x >> 2, pt = blockIdx.x & 3;
  const int mg = wave >> 1, ng = wave & 1;
  const uint16_t* Abase = Gsw + (size_t)t * 524288;
  const uint16_t* Bbase = WdS + (size_t)pt * 524288;
  f32x4 acc[2][4];
#pragma unroll
  for (int i = 0; i < 2; i++)
#pragma unroll
    for (int j = 0; j < 4; j++) acc[i][j] = (f32x4){0.f, 0.f, 0.f, 0.f};

  for (int chunk = 0; chunk < 32; chunk++) {
    const uint16_t* Ac = Abase + ((size_t)chunk << 14);
    const uint16_t* Bc = Bbase + ((size_t)chunk << 14);
#pragma unroll
    for (int i = 0; i < 8; i++) {
      const int j = wave * 8 + i;
      const uint16_t* s = (j < 32) ? (Ac + (j << 9)) : (Bc + ((j - 32) << 9));
      gl2lds16(s + (lane << 3), (void*)(lds + (j << 9)));
    }
    __syncthreads();
    const uint16_t* lA = lds;
    const uint16_t* lB = lds + 16384;
#pragma unroll
    for (int ktl = 0; ktl < 4; ktl++) {
      bf16x8 a0 = *(const bf16x8*)(lA + ((((mg * 2 + 0) * 4 + ktl) * 64 + lane) << 3));
      bf16x8 a1 = *(const bf16x8*)(lA + ((((mg * 2 + 1) * 4 + ktl) * 64 + lane) << 3));
#pragma unroll
      for (int nt = 0; nt < 4; nt++) {
        bf16x8 b = *(const bf16x8*)(lB + ((((ng * 4 + nt) * 4 + ktl) * 64 + lane) << 3));
        acc[0][nt] = __builtin_amdgcn_mfma_f32_16x16x32_bf16(a0, b, acc[0][nt], 0, 0, 0);
        acc[1][nt] = __builtin_amdgcn_mfma_f32_16x16x32_bf16(a1, b, acc[1][nt], 0, 0, 0);
      }
    }
    __syncthreads();
  }
  const int p0c = (pt << 7) + (ng << 6);
  const int rb = (mg << 5) + ((lane >> 4) << 2);
#pragma unroll
  for (int mi = 0; mi < 2; mi++)
#pragma unroll
    for (int nt = 0; nt < 4; nt++) {
      const int p = p0c + (nt << 4) + (lane & 15);
      const float bias = bd[p];
#pragma unroll
      for (int r = 0; r < 4; r++) {
        const int b = rb + (mi << 4) + r;
        out[((size_t)b * kT + t) * kNP + p] = acc[mi][nt][r] + bias;
      }
    }
}

extern "C" void kernel_launch(void* const* d_in, const int* in_sizes, int n_in,
                              void* d_out, int out_size, void* d_ws, size_t ws_size,
                              hipStream_t stream) {
  const float* v    = (const float*)d_in[0];
  const float* p0   = (const float*)d_in[1];
  const float* Wenc = (const float*)d_in[2];
  const float* Wih  = (const float*)d_in[3];
  const float* Whh  = (const float*)d_in[4];
  const float* Wdec = (const float*)d_in[5];
  const float* bdec = (const float*)d_in[6];
  float* out = (float*)d_out;

  uint8_t* ws = (uint8_t*)d_ws;
  uint16_t* WhS = (uint16_t*)(ws);
  uint16_t* WdS = (uint16_t*)(ws + 33554432);
  uint16_t* H0S = (uint16_t*)(ws + 37748736);
  uint16_t* Gsw = (uint16_t*)(ws + 38797312);
  float*    Part = (float*)(ws + 143654912);
  int*      flags = (int*)(ws + 160432128);

  cvt_whh_kernel<<<4096, 512, 0, stream>>>(Whh, WhS, flags);
  cvt_wdec_kernel<<<512, 512, 0, stream>>>(Wdec, WdS);
  enc_kernel<<<256, 512, 0, stream>>>(p0, Wenc, H0S);

  // persistent flag-synced RNN loop (cooperative launch for residency guarantee)
  const uint16_t* WhS_c = WhS;
  const uint16_t* H0S_c = H0S;
  void* args[7] = {(void*)&WhS_c, (void*)&H0S_c, (void*)&Gsw, (void*)&Part,
                   (void*)&v, (void*)&Wih, (void*)&flags};
  hipError_t e = hipLaunchCooperativeKernel(rnn_loop_kernel, dim3(256), dim3(512), args,
                                            (unsigned int)131072, stream);
  if (e != hipSuccess) {
    // fallback: per-step launches (round-1 path, ~1.96 ms class)
    (void)hipGetLastError();
    for (int t = 0; t < kT; t++) {
      const uint16_t* Asrc = (t == 0) ? H0S : (Gsw + (size_t)(t - 1) * 524288);
      stepmm_kernel<<<256, 512, 0, stream>>>(Asrc, WhS, Part);
      steptanh_kernel<<<256, 256, 0, stream>>>(Part, v, Wih, Gsw + (size_t)t * 524288, t);
    }
  }

  dec_kernel<<<400, 512, 0, stream>>>(Gsw, WdS, bdec, out);
}

// Round 9
// 1296.022 us; speedup vs baseline: 3.0721x; 1.0429x over previous
//
// RNN_79577154060490 — round 10: round-6 verified base + parallel stamp flags
// (isolated; no cache-op changes). h0=p0@W_enc^T; 100x h=tanh(v@W_ih^T+h@W_hh^T);
// out = g@W_dec^T + b
//
// Round-9 post-mortem: buffer_inv+plain-reads REGRESSED (947->1130) and WRITE
// stayed 15MB/step -> Part's L2->MALL eviction is capacity-driven, not read-
// flavor-driven; the inv was pure cost. Stamps were confounded — isolated here.
// Round-6 residual theory: pcnt/hcnt do 8 serialized RMWs on ONE LLC word,
// twice per step (~2.3us first-to-last spread each), and the gt<->chunk
// dependency web globalizes that skew.
// Round-10 changes vs round 6 (one mechanism):
//  * counters -> single-writer STAMPS: pstamp/hstamp[gt*8+ks]=t+1 via agent
//    atomic-exchange (8 PARALLEL RMWs on independent words); polls are parallel
//    lane loads (32 RAW words pre-mm; 8 words per rendezvous).
//  * WAR poll (readers of my Part done with t-1) moved AFTER mm (mm doesn't
//    touch Part) -> off the critical path, hits first try.
//  * keep: Part normal stores + sc0 reads (round-6 verified), h publish via
//    agent atomic-exchange, W_hh LDS-resident, Wih hoist, v(t) prefetch.
//
// ws layout (bytes):
//   [0,         33554432)   WhS  bf16 [gt32][chunk32][nt8][ktl4][64][8]
//   [33554432,  37748736)   WdS  bf16 [pt4][chunk32][nt8][ktl4][64][8]
//   [37748736,  38797312)   H0S  bf16 A-image (1MB)
//   [38797312, 143654912)   Gsw  bf16 [t100] A-images (100MB)
//   [143654912,160432128)   Part fp32 [gt32][ks8][128][128] (16MB)
//   [160432128,160440320)   flags int[2048]: pstamp[256] @0; hstamp[256] @+256

#include <hip/hip_runtime.h>
#include <stdint.h>

namespace {
constexpr int kT = 100;
constexpr int kNG = 4096;
constexpr int kNP = 512;

__device__ __forceinline__ uint16_t f2bf(float f) {
  uint32_t u = __float_as_uint(f);
  u += 0x7FFFu + ((u >> 16) & 1u);
  return (uint16_t)(u >> 16);
}

__device__ __forceinline__ float fast_tanh(float x) {
  float xc = fminf(fmaxf(x, -15.f), 15.f);
  float e = __expf(2.f * xc);
  return (e - 1.f) / (e + 1.f);
}

__device__ __forceinline__ void gl2lds16(const void* g, void* l) {
  __builtin_amdgcn_global_load_lds((const __attribute__((address_space(1))) unsigned int*)g,
                                   (__attribute__((address_space(3))) unsigned int*)l, 16, 0, 0);
}

// fragment-image element offsets (within one tensor)
__device__ __forceinline__ size_t a_img_off(int b, int g) {  // g = k index
  return ((size_t)(((g >> 7) * 8 + (b >> 4)) * 4 + ((g >> 5) & 3)) * 64 +
          ((g >> 3) & 3) * 16 + (b & 15)) * 8 + (g & 7);
}
}  // namespace

typedef short bf16x8 __attribute__((ext_vector_type(8)));
typedef float f32x4 __attribute__((ext_vector_type(4)));

// ---- swizzle-convert W_hh fp32 [4096][4096] -> WhS B-image bf16 (+flag zero) ----
__global__ __launch_bounds__(512) void cvt_whh_kernel(const float* __restrict__ W,
                                                      uint16_t* __restrict__ WhS,
                                                      int* __restrict__ flags) {
  if (blockIdx.x == 4095) {
    for (int i = threadIdx.x; i < 2048; i += 512) flags[i] = 0;
  }
  const int idx = blockIdx.x * 512 + threadIdx.x;  // 2M threads
  const int g = idx >> 9;
  const int k0 = (idx & 511) << 3;
  const float4 x = *(const float4*)(W + (size_t)g * kNG + k0);
  const float4 y = *(const float4*)(W + (size_t)g * kNG + k0 + 4);
  uint4 u;
  u.x = (uint32_t)f2bf(x.x) | ((uint32_t)f2bf(x.y) << 16);
  u.y = (uint32_t)f2bf(x.z) | ((uint32_t)f2bf(x.w) << 16);
  u.z = (uint32_t)f2bf(y.x) | ((uint32_t)f2bf(y.y) << 16);
  u.w = (uint32_t)f2bf(y.z) | ((uint32_t)f2bf(y.w) << 16);
  const int gt = g >> 7, c = g & 127;
  const int nt = c >> 4, col = c & 15;
  const int chunk = k0 >> 7, ktl = (k0 >> 5) & 3, half = (k0 >> 3) & 3;
  const size_t off = ((size_t)(((gt * 32 + chunk) * 8 + nt) * 4 + ktl) * 64 + half * 16 + col) * 8;
  *(uint4*)(WhS + off) = u;
}

// ---- swizzle-convert W_dec fp32 [512][4096] -> WdS B-image bf16 ----
__global__ __launch_bounds__(512) void cvt_wdec_kernel(const float* __restrict__ W,
                                                       uint16_t* __restrict__ WdS) {
  const int idx = blockIdx.x * 512 + threadIdx.x;  // 256K threads
  const int p = idx >> 9;
  const int k0 = (idx & 511) << 3;
  const float4 x = *(const float4*)(W + (size_t)p * kNG + k0);
  const float4 y = *(const float4*)(W + (size_t)p * kNG + k0 + 4);
  uint4 u;
  u.x = (uint32_t)f2bf(x.x) | ((uint32_t)f2bf(x.y) << 16);
  u.y = (uint32_t)f2bf(x.z) | ((uint32_t)f2bf(x.w) << 16);
  u.z = (uint32_t)f2bf(y.x) | ((uint32_t)f2bf(y.y) << 16);
  u.w = (uint32_t)f2bf(y.z) | ((uint32_t)f2bf(y.w) << 16);
  const int pt = p >> 7, c = p & 127;
  const int nt = c >> 4, col = c & 15;
  const int chunk = k0 >> 7, ktl = (k0 >> 5) & 3, half = (k0 >> 3) & 3;
  const size_t off = ((size_t)(((pt * 32 + chunk) * 8 + nt) * 4 + ktl) * 64 + half * 16 + col) * 8;
  *(uint4*)(WdS + off) = u;
}

// ---- encoder: H0S = A-image of p0 @ Wenc^T (bf16) ----
__global__ __launch_bounds__(512, 2) void enc_kernel(const float* __restrict__ p0,
                                                     const float* __restrict__ Wenc,
                                                     uint16_t* __restrict__ H0S) {
  __shared__ alignas(16) uint16_t Wlds[16 * 64 * 8];
  const int tid = threadIdx.x;
  const int g0 = blockIdx.x * 16;
  for (int f = tid; f < 16 * 64; f += 512) {
    const int kt = f >> 6, fl = f & 63;
    const int g = g0 + (fl & 15);
    const int k = kt * 32 + ((fl >> 4) << 3);
    const float* s = Wenc + (size_t)g * kNP + k;
    uint16_t* d = Wlds + f * 8;
#pragma unroll
    for (int j = 0; j < 8; j++) d[j] = f2bf(s[j]);
  }
  __syncthreads();
  const int wave = tid >> 6;
  const int lane = tid & 63;
  const int mrow = wave * 16 + (lane & 15);
  const float* arow = p0 + (size_t)mrow * kNP + ((lane >> 4) << 3);
  f32x4 acc = {0.f, 0.f, 0.f, 0.f};
#pragma unroll
  for (int kt = 0; kt < 16; kt++) {
    const float* ap = arow + kt * 32;
    bf16x8 a;
#pragma unroll
    for (int j = 0; j < 8; j++) a[j] = (short)f2bf(ap[j]);
    bf16x8 b = *(const bf16x8*)(Wlds + (kt * 64 + lane) * 8);
    acc = __builtin_amdgcn_mfma_f32_16x16x32_bf16(a, b, acc, 0, 0, 0);
  }
  const int gcol = g0 + (lane & 15);
  const int rbase = wave * 16 + ((lane >> 4) << 2);
#pragma unroll
  for (int r = 0; r < 4; r++) {
    H0S[a_img_off(rbase + r, gcol)] = f2bf(acc[r]);
  }
}

// ---- persistent RNN loop: block-synchronous, parallel stamp flags ----
__global__ __launch_bounds__(512, 2) void rnn_loop_kernel(const uint16_t* __restrict__ WhS,
                                                          const uint16_t* __restrict__ H0S,
                                                          uint16_t* __restrict__ Gsw,
                                                          float* __restrict__ Part,
                                                          const float* __restrict__ v,
                                                          const float* __restrict__ Wih,
                                                          int* __restrict__ flags) {
  extern __shared__ uint16_t wlds[];  // 131072 B
  const int tid = threadIdx.x;
  const int wave = tid >> 6, lane = tid & 63;
  const int bid = blockIdx.x;
  const int xcd = bid & 7;                 // dispatch round-robin heuristic (perf-only)
  const int gt = xcd * 4 + (bid >> 6);     // all 8 ks-blocks of gt on one XCD
  const int ks = (bid >> 3) & 7;
  const int mg = wave >> 1, ng = wave & 1;

  int* pstamp = flags;        // [gt*8+ks] = t+1 when Part slice ready (LLC)
  int* hstamp = flags + 256;  // [gt*8+ks] = t+1 when reduce of step t done (LLC)

  // one-time: W tile (row gt, chunks ks*4..+3) -> LDS, linear copy
  {
    const uint16_t* src = WhS + ((size_t)gt << 19) + ((size_t)(ks * 4) << 14);
#pragma unroll
    for (int i = 0; i < 16; i++) {
      const int j = wave * 16 + i;
      gl2lds16(src + (j << 9) + (lane << 3), (void*)(wlds + (j << 9)));
    }
  }
  __syncthreads();

  // reduce-phase coords: 16 rows x 128 g per block, 4 g per thread
  const int rbred = ks * 16 + (tid >> 5);  // batch row
  const int gl = (tid & 31) << 2;          // local g 0..124
  const int gg = gt * 128 + gl;            // global g
  float* myPart = Part + (((size_t)(gt * 8 + ks)) << 14);

  // loop-invariant Wih rows for this thread's 4 g (hoisted out of t-loop)
  const float4 w0 = *(const float4*)(Wih + gg * 2);
  const float4 w1 = *(const float4*)(Wih + gg * 2 + 4);

  for (int t = 0; t < kT; t++) {
    // ---- RAW-only wait: h(t-1) chunks ks*4..+3 (8 writer blocks each) ----
    if (t > 0) {
      if (tid < 32) {
        int* f = hstamp + (ks * 4 + (tid >> 3)) * 8 + (tid & 7);
        while (__hip_atomic_load(f, __ATOMIC_RELAXED, __HIP_MEMORY_SCOPE_AGENT) < t)
          __builtin_amdgcn_s_sleep(1);
      }
      __builtin_amdgcn_fence(__ATOMIC_ACQUIRE, "workgroup");  // compiler order; no cache op
      __syncthreads();
    }

    // prefetch v(t) for the reduce phase (latency hides under mm)
    const float v0 = v[(rbred * kT + t) * 2 + 0];
    const float v1 = v[(rbred * kT + t) * 2 + 1];

    const uint16_t* Aimg = (t == 0) ? H0S : (Gsw + (((size_t)(t - 1)) << 19));
    f32x4 acc[2][4];
#pragma unroll
    for (int i = 0; i < 2; i++)
#pragma unroll
      for (int j = 0; j < 4; j++) acc[i][j] = (f32x4){0.f, 0.f, 0.f, 0.f};

#pragma unroll
    for (int kc = 0; kc < 4; kc++) {
      const uint16_t* Ac = Aimg + ((size_t)(ks * 4 + kc) << 14);
      bf16x8 a[2][4];
#pragma unroll
      for (int mi = 0; mi < 2; mi++)
#pragma unroll
        for (int ktl = 0; ktl < 4; ktl++)
          a[mi][ktl] = *(const bf16x8*)(Ac + ((((mg * 2 + mi) * 4 + ktl) * 64 + lane) << 3));
#pragma unroll
      for (int ktl = 0; ktl < 4; ktl++) {
#pragma unroll
        for (int nt = 0; nt < 4; nt++) {
          bf16x8 b = *(const bf16x8*)(wlds + (kc << 14) +
                                      ((((ng * 4 + nt) * 4 + ktl) * 64 + lane) << 3));
          acc[0][nt] = __builtin_amdgcn_mfma_f32_16x16x32_bf16(a[0][ktl], b, acc[0][nt], 0, 0, 0);
          acc[1][nt] = __builtin_amdgcn_mfma_f32_16x16x32_bf16(a[1][ktl], b, acc[1][nt], 0, 0, 0);
        }
      }
    }

    // ---- WAR check (post-mm, off critical path): readers of my Part group
    //      finished step t-1 (they stamp hstamp[gt*8+j]=t when done) ----
    if (t > 0) {
      if (lane < 8) {  // per-wave poll, no barrier; hits first try in practice
        int* f = hstamp + gt * 8 + lane;
        while (__hip_atomic_load(f, __ATOMIC_RELAXED, __HIP_MEMORY_SCOPE_AGENT) < t)
          __builtin_amdgcn_s_sleep(1);
      }
    }

    // Part write: normal stores -> XCD-shared L2
    {
      const int gcol0 = (ng << 6);
      const int rbase = (mg << 5) + ((lane >> 4) << 2);
#pragma unroll
      for (int mi = 0; mi < 2; mi++)
#pragma unroll
        for (int nt = 0; nt < 4; nt++)
#pragma unroll
          for (int r = 0; r < 4; r++) {
            const int b = rbase + (mi << 4) + r;
            const int g = gcol0 + (nt << 4) + (lane & 15);
            myPart[(b << 7) + g] = acc[mi][nt][r];
          }
    }
    asm volatile("s_waitcnt vmcnt(0)" ::: "memory");  // this wave's Part in L2
    __syncthreads();                                   // all waves' Part in L2
    if (tid == 0)  // stamp Part-ready (independent word; parallel across blocks)
      __hip_atomic_exchange(pstamp + gt * 8 + ks, t + 1, __ATOMIC_RELAXED,
                            __HIP_MEMORY_SCOPE_AGENT);
    if (tid < 8) {  // wait all 8 slices of this gt (parallel lane loads)
      while (__hip_atomic_load(pstamp + gt * 8 + tid, __ATOMIC_RELAXED,
                               __HIP_MEMORY_SCOPE_AGENT) < t + 1)
        __builtin_amdgcn_s_sleep(1);
    }
    __builtin_amdgcn_fence(__ATOMIC_ACQUIRE, "workgroup");  // compiler order only
    __syncthreads();

    // reduce rows [16ks..+16) over 8 slices + vin + tanh -> Gsw[t] A-image.
    // Part reads: sc0 (bypass stale L1; hit shared L2 / MALL). [round-6 verified]
    {
      const float* pb = Part + (((size_t)(gt * 8)) << 14) + (rbred << 7) + gl;
      f32x4 pv[8];
#pragma unroll
      for (int j = 0; j < 8; j++) {
        asm volatile("global_load_dwordx4 %0, %1, off sc0"
                     : "=v"(pv[j])
                     : "v"(pb + ((size_t)j << 14))
                     : "memory");
      }
      asm volatile("s_waitcnt vmcnt(0)" ::: "memory");
      __builtin_amdgcn_sched_barrier(0);  // rule #18: keep VALU below the waitcnt
      float s0 = 0.f, s1 = 0.f, s2 = 0.f, s3 = 0.f;
#pragma unroll
      for (int j = 0; j < 8; j++) {
        s0 += pv[j][0]; s1 += pv[j][1]; s2 += pv[j][2]; s3 += pv[j][3];
      }
      const uint16_t h0 = f2bf(fast_tanh(s0 + v0 * w0.x + v1 * w0.y));
      const uint16_t h1 = f2bf(fast_tanh(s1 + v0 * w0.z + v1 * w0.w));
      const uint16_t h2 = f2bf(fast_tanh(s2 + v0 * w1.x + v1 * w1.y));
      const uint16_t h3 = f2bf(fast_tanh(s3 + v0 * w1.z + v1 * w1.w));
      const uint32_t lo = (uint32_t)h0 | ((uint32_t)h1 << 16);
      const uint32_t hi = (uint32_t)h2 | ((uint32_t)h3 << 16);
      const unsigned long long uval = ((unsigned long long)hi << 32) | lo;
      uint16_t* Gt = Gsw + (((size_t)t) << 19);
      // h publish: atomic swap executes at the LLC (agent coherence point)
      __hip_atomic_exchange((unsigned long long*)(Gt + a_img_off(rbred, gg)), uval,
                            __ATOMIC_RELAXED, __HIP_MEMORY_SCOPE_AGENT);
    }
    asm volatile("s_waitcnt vmcnt(0)" ::: "memory");  // this wave's h at LLC
    __syncthreads();                                   // whole block's h at LLC
    if (tid == 0)  // stamp reduce-done (independent word)
      __hip_atomic_exchange(hstamp + gt * 8 + ks, t + 1, __ATOMIC_RELAXED,
                            __HIP_MEMORY_SCOPE_AGENT);
  }
}

// ---- fallback step kernels (used only if cooperative launch is refused) ----
__global__ __launch_bounds__(512, 4) void stepmm_kernel(const uint16_t* __restrict__ Asrc,
                                                        const uint16_t* __restrict__ WhS,
                                                        float* __restrict__ Part) {
  __shared__ alignas(16) uint16_t lds[32768];
  const int tid = threadIdx.x;
  const int wave = tid >> 6, lane = tid & 63;
  const int gt = blockIdx.x >> 3, ks = blockIdx.x & 7;
  const int mg = wave >> 1, ng = wave & 1;
  const uint16_t* Wbase = WhS + ((size_t)gt << 19);
  f32x4 acc[2][4];
#pragma unroll
  for (int i = 0; i < 2; i++)
#pragma unroll
    for (int j = 0; j < 4; j++) acc[i][j] = (f32x4){0.f, 0.f, 0.f, 0.f};

  for (int kc = 0; kc < 4; kc++) {
    const int chunk = ks * 4 + kc;
    const uint16_t* Ac = Asrc + ((size_t)chunk << 14);
    const uint16_t* Bc = Wbase + ((size_t)chunk << 14);
#pragma unroll
    for (int i = 0; i < 8; i++) {
      const int j = wave * 8 + i;
      const uint16_t* s = (j < 32) ? (Ac + (j << 9)) : (Bc + ((j - 32) << 9));
      gl2lds16(s + (lane << 3), (void*)(lds + (j << 9)));
    }
    __syncthreads();
    const uint16_t* lA = lds;
    const uint16_t* lB = lds + 16384;
#pragma unroll
    for (int ktl = 0; ktl < 4; ktl++) {
      bf16x8 a0 = *(const bf16x8*)(lA + ((((mg * 2 + 0) * 4 + ktl) * 64 + lane) << 3));
      bf16x8 a1 = *(const bf16x8*)(lA + ((((mg * 2 + 1) * 4 + ktl) * 64 + lane) << 3));
#pragma unroll
      for (int nt = 0; nt < 4; nt++) {
        bf16x8 b = *(const bf16x8*)(lB + ((((ng * 4 + nt) * 4 + ktl) * 64 + lane) << 3));
        acc[0][nt] = __builtin_amdgcn_mfma_f32_16x16x32_bf16(a0, b, acc[0][nt], 0, 0, 0);
        acc[1][nt] = __builtin_amdgcn_mfma_f32_16x16x32_bf16(a1, b, acc[1][nt], 0, 0, 0);
      }
    }
    __syncthreads();
  }
  const int g0 = (gt << 7) + (ng << 6);
  const int rb = (mg << 5) + ((lane >> 4) << 2);
#pragma unroll
  for (int mi = 0; mi < 2; mi++)
#pragma unroll
    for (int nt = 0; nt < 4; nt++)
#pragma unroll
      for (int r = 0; r < 4; r++) {
        const int b = rb + (mi << 4) + r;
        const int g = g0 + (nt << 4) + (lane & 15);
        Part[(((size_t)(ks * 128 + b)) << 12) + g] = acc[mi][nt][r];
      }
}

__global__ __launch_bounds__(256) void steptanh_kernel(const float* __restrict__ Part,
                                                       const float* __restrict__ v,
                                                       const float* __restrict__ Wih,
                                                       uint16_t* __restrict__ Gt, int t) {
  const int tg = blockIdx.x * 256 + threadIdx.x;
  const int b = tg >> 9;
  const int g0 = (tg & 511) << 3;
  float s[8];
#pragma unroll
  for (int j = 0; j < 8; j++) s[j] = 0.f;
#pragma unroll
  for (int ks = 0; ks < 8; ks++) {
    const float4* p = (const float4*)(Part + (((size_t)(ks * 128 + b)) << 12) + g0);
    const float4 x = p[0], y = p[1];
    s[0] += x.x; s[1] += x.y; s[2] += x.z; s[3] += x.w;
    s[4] += y.x; s[5] += y.y; s[6] += y.z; s[7] += y.w;
  }
  const float v0 = v[(b * kT + t) * 2 + 0];
  const float v1 = v[(b * kT + t) * 2 + 1];
  uint16_t h[8];
#pragma unroll
  for (int j = 0; j < 8; j++) {
    const int g = g0 + j;
    const float pre = s[j] + v0 * Wih[g * 2 + 0] + v1 * Wih[g * 2 + 1];
    h[j] = f2bf(fast_tanh(pre));
  }
  uint4 u;
  u.x = (uint32_t)h[0] | ((uint32_t)h[1] << 16);
  u.y = (uint32_t)h[2] | ((uint32_t)h[3] << 16);
  u.z = (uint32_t)h[4] | ((uint32_t)h[5] << 16);
  u.w = (uint32_t)h[6] | ((uint32_t)h[7] << 16);
  const size_t off = ((size_t)(((g0 >> 7) * 8 + (b >> 4)) * 4 + ((g0 >> 5) & 3)) * 64 +
                      ((g0 >> 3) & 3) * 16 + (b & 15)) * 8;
  *(uint4*)(Gt + off) = u;
}

// ---- decoder: out[b,t,p] = Gsw[t] @ WdS[pt] + bias. block=(t, pt), 32 k-chunks ----
__global__ __launch_bounds__(512, 4) void dec_kernel(const uint16_t* __restrict__ Gsw,
                                                     const uint16_t* __restrict__ WdS,
                                                     const float* __restrict__ bd,
                                                     float* __restrict__ out) {
  __shared__ alignas(16) uint16_t lds[32768];
  const int tid = threadIdx.x;
  const int wave = tid >> 6, lane = tid & 63;
  const int t = blockIdx.x >> 2, pt = blockIdx.x & 3;
  const int mg = wave >> 1, ng = wave & 1;
  const uint16_t* Abase = Gsw + (size_t)t * 524288;
  const uint16_t* Bbase = WdS + (size_t)pt * 524288;
  f32x4 acc[2][4];
#pragma unroll
  for (int i = 0; i < 2; i++)
#pragma unroll
    for (int j = 0; j < 4; j++) acc[i][j] = (f32x4){0.f, 0.f, 0.f, 0.f};

  for (int chunk = 0; chunk < 32; chunk++) {
    const uint16_t* Ac = Abase + ((size_t)chunk << 14);
    const uint16_t* Bc = Bbase + ((size_t)chunk << 14);
#pragma unroll
    for (int i = 0; i < 8; i++) {
      const int j = wave * 8 + i;
      const uint16_t* s = (j < 32) ? (Ac + (j << 9)) : (Bc + ((j - 32) << 9));
      gl2lds16(s + (lane << 3), (void*)(lds + (j << 9)));
    }
    __syncthreads();
    const uint16_t* lA = lds;
    const uint16_t* lB = lds + 16384;
#pragma unroll
    for (int ktl = 0; ktl < 4; ktl++) {
      bf16x8 a0 = *(const bf16x8*)(lA + ((((mg * 2 + 0) * 4 + ktl) * 64 + lane) << 3));
      bf16x8 a1 = *(const bf16x8*)(lA + ((((mg * 2 + 1) * 4 + ktl) * 64 + lane) << 3));
#pragma unroll
      for (int nt = 0; nt < 4; nt++) {
        bf16x8 b = *(const bf16x8*)(lB + ((((ng * 4 + nt) * 4 + ktl) * 64 + lane) << 3));
        acc[0][nt] = __builtin_amdgcn_mfma_f32_16x16x32_bf16(a0, b, acc[0][nt], 0, 0, 0);
        acc[1][nt] = __builtin_amdgcn_mfma_f32_16x16x32_bf16(a1, b, acc[1][nt], 0, 0, 0);
      }
    }
    __syncthreads();
  }
  const int p0c = (pt << 7) + (ng << 6);
  const int rb = (mg << 5) + ((lane >> 4) << 2);
#pragma unroll
  for (int mi = 0; mi < 2; mi++)
#pragma unroll
    for (int nt = 0; nt < 4; nt++) {
      const int p = p0c + (nt << 4) + (lane & 15);
      const float bias = bd[p];
#pragma unroll
      for (int r = 0; r < 4; r++) {
        const int b = rb + (mi << 4) + r;
        out[((size_t)b * kT + t) * kNP + p] = acc[mi][nt][r] + bias;
      }
    }
}

extern "C" void kernel_launch(void* const* d_in, const int* in_sizes, int n_in,
                              void* d_out, int out_size, void* d_ws, size_t ws_size,
                              hipStream_t stream) {
  const float* v    = (const float*)d_in[0];
  const float* p0   = (const float*)d_in[1];
  const float* Wenc = (const float*)d_in[2];
  const float* Wih  = (const float*)d_in[3];
  const float* Whh  = (const float*)d_in[4];
  const float* Wdec = (const float*)d_in[5];
  const float* bdec = (const float*)d_in[6];
  float* out = (float*)d_out;

  uint8_t* ws = (uint8_t*)d_ws;
  uint16_t* WhS = (uint16_t*)(ws);
  uint16_t* WdS = (uint16_t*)(ws + 33554432);
  uint16_t* H0S = (uint16_t*)(ws + 37748736);
  uint16_t* Gsw = (uint16_t*)(ws + 38797312);
  float*    Part = (float*)(ws + 143654912);
  int*      flags = (int*)(ws + 160432128);

  cvt_whh_kernel<<<4096, 512, 0, stream>>>(Whh, WhS, flags);
  cvt_wdec_kernel<<<512, 512, 0, stream>>>(Wdec, WdS);
  enc_kernel<<<256, 512, 0, stream>>>(p0, Wenc, H0S);

  // persistent flag-synced RNN loop (cooperative launch for residency guarantee)
  const uint16_t* WhS_c = WhS;
  const uint16_t* H0S_c = H0S;
  void* args[7] = {(void*)&WhS_c, (void*)&H0S_c, (void*)&Gsw, (void*)&Part,
                   (void*)&v, (void*)&Wih, (void*)&flags};
  hipError_t e = hipLaunchCooperativeKernel(rnn_loop_kernel, dim3(256), dim3(512), args,
                                            (unsigned int)131072, stream);
  if (e != hipSuccess) {
    // fallback: per-step launches (round-1 path, ~1.96 ms class)
    (void)hipGetLastError();
    for (int t = 0; t < kT; t++) {
      const uint16_t* Asrc = (t == 0) ? H0S : (Gsw + (size_t)(t - 1) * 524288);
      stepmm_kernel<<<256, 512, 0, stream>>>(Asrc, WhS, Part);
      steptanh_kernel<<<256, 256, 0, stream>>>(Part, v, Wih, Gsw + (size_t)t * 524288, t);
    }
  }

  dec_kernel<<<400, 512, 0, stream>>>(Gsw, WdS, bdec, out);
}

// Round 10
// 1132.064 us; speedup vs baseline: 3.5170x; 1.1448x over previous
//
// RNN_79577154060490 — round 11: consolidation. Loop = exact round-6 verified
// protocol (947us); new mechanism isolated to DECODER: XCD-swizzled grid so the
// 4 pt-blocks sharing Gsw[t] land on one XCD's L2 (T1).
// h0=p0@W_enc^T; 100x h=tanh(v@W_ih^T+h@W_hh^T); out = g@W_dec^T + b
//
// Sync-mechanics ledger (all vs round-6's 947us loop):
//   r7 per-wave flags: 3430us (8x LLC RMW+spin). r9 buffer_inv+plain: 1130us.
//   r10 parallel stamps: 1078us (wide polls > RMW serialization).
//   => round-6 relaxed-counter protocol is the local optimum; frozen here.
// Loop protocol (round-6, verified): W_hh LDS-resident; A plain cached; Part
// normal stores + sc0 reads; h via agent atomic-exchange (LLC); pcnt/hcnt
// relaxed counter rendezvous (tid<5 RAW+WAR wait, tid0 agents). Micro-opts
// kept: Wih hoisted, v(t) prefetched (register-level, mechanically safe).
// Decoder change: bid -> (slot=bid&7, m=bid>>3): t=slot+8*(m>>2), pt=m&3.
// All 4 pt of a given t are bid-adjacent in one slot => same XCD => Gsw[t]
// fetched once per XCD. grid 416 (guard t<100).
//
// ws layout (bytes):
//   [0,         33554432)   WhS  bf16 [gt32][chunk32][nt8][ktl4][64][8]
//   [33554432,  37748736)   WdS  bf16 [pt4][chunk32][nt8][ktl4][64][8]
//   [37748736,  38797312)   H0S  bf16 A-image (1MB)
//   [38797312, 143654912)   Gsw  bf16 [t100] A-images (100MB)
//   [143654912,160432128)   Part fp32 [gt32][ks8][128][128] (16MB)
//   [160432128,160440320)   flags int[2048] (pcnt[32] @0, hcnt[32] @+1024; stride 32)

#include <hip/hip_runtime.h>
#include <stdint.h>

namespace {
constexpr int kT = 100;
constexpr int kNG = 4096;
constexpr int kNP = 512;

__device__ __forceinline__ uint16_t f2bf(float f) {
  uint32_t u = __float_as_uint(f);
  u += 0x7FFFu + ((u >> 16) & 1u);
  return (uint16_t)(u >> 16);
}

__device__ __forceinline__ float fast_tanh(float x) {
  float xc = fminf(fmaxf(x, -15.f), 15.f);
  float e = __expf(2.f * xc);
  return (e - 1.f) / (e + 1.f);
}

__device__ __forceinline__ void gl2lds16(const void* g, void* l) {
  __builtin_amdgcn_global_load_lds((const __attribute__((address_space(1))) unsigned int*)g,
                                   (__attribute__((address_space(3))) unsigned int*)l, 16, 0, 0);
}

// fragment-image element offsets (within one tensor)
__device__ __forceinline__ size_t a_img_off(int b, int g) {  // g = k index
  return ((size_t)(((g >> 7) * 8 + (b >> 4)) * 4 + ((g >> 5) & 3)) * 64 +
          ((g >> 3) & 3) * 16 + (b & 15)) * 8 + (g & 7);
}
}  // namespace

typedef short bf16x8 __attribute__((ext_vector_type(8)));
typedef float f32x4 __attribute__((ext_vector_type(4)));

// ---- swizzle-convert W_hh fp32 [4096][4096] -> WhS B-image bf16 (+flag zero) ----
__global__ __launch_bounds__(512) void cvt_whh_kernel(const float* __restrict__ W,
                                                      uint16_t* __restrict__ WhS,
                                                      int* __restrict__ flags) {
  if (blockIdx.x == 4095) {
    for (int i = threadIdx.x; i < 2048; i += 512) flags[i] = 0;
  }
  const int idx = blockIdx.x * 512 + threadIdx.x;  // 2M threads
  const int g = idx >> 9;
  const int k0 = (idx & 511) << 3;
  const float4 x = *(const float4*)(W + (size_t)g * kNG + k0);
  const float4 y = *(const float4*)(W + (size_t)g * kNG + k0 + 4);
  uint4 u;
  u.x = (uint32_t)f2bf(x.x) | ((uint32_t)f2bf(x.y) << 16);
  u.y = (uint32_t)f2bf(x.z) | ((uint32_t)f2bf(x.w) << 16);
  u.z = (uint32_t)f2bf(y.x) | ((uint32_t)f2bf(y.y) << 16);
  u.w = (uint32_t)f2bf(y.z) | ((uint32_t)f2bf(y.w) << 16);
  const int gt = g >> 7, c = g & 127;
  const int nt = c >> 4, col = c & 15;
  const int chunk = k0 >> 7, ktl = (k0 >> 5) & 3, half = (k0 >> 3) & 3;
  const size_t off = ((size_t)(((gt * 32 + chunk) * 8 + nt) * 4 + ktl) * 64 + half * 16 + col) * 8;
  *(uint4*)(WhS + off) = u;
}

// ---- swizzle-convert W_dec fp32 [512][4096] -> WdS B-image bf16 ----
__global__ __launch_bounds__(512) void cvt_wdec_kernel(const float* __restrict__ W,
                                                       uint16_t* __restrict__ WdS) {
  const int idx = blockIdx.x * 512 + threadIdx.x;  // 256K threads
  const int p = idx >> 9;
  const int k0 = (idx & 511) << 3;
  const float4 x = *(const float4*)(W + (size_t)p * kNG + k0);
  const float4 y = *(const float4*)(W + (size_t)p * kNG + k0 + 4);
  uint4 u;
  u.x = (uint32_t)f2bf(x.x) | ((uint32_t)f2bf(x.y) << 16);
  u.y = (uint32_t)f2bf(x.z) | ((uint32_t)f2bf(x.w) << 16);
  u.z = (uint32_t)f2bf(y.x) | ((uint32_t)f2bf(y.y) << 16);
  u.w = (uint32_t)f2bf(y.z) | ((uint32_t)f2bf(y.w) << 16);
  const int pt = p >> 7, c = p & 127;
  const int nt = c >> 4, col = c & 15;
  const int chunk = k0 >> 7, ktl = (k0 >> 5) & 3, half = (k0 >> 3) & 3;
  const size_t off = ((size_t)(((pt * 32 + chunk) * 8 + nt) * 4 + ktl) * 64 + half * 16 + col) * 8;
  *(uint4*)(WdS + off) = u;
}

// ---- encoder: H0S = A-image of p0 @ Wenc^T (bf16) ----
__global__ __launch_bounds__(512, 2) void enc_kernel(const float* __restrict__ p0,
                                                     const float* __restrict__ Wenc,
                                                     uint16_t* __restrict__ H0S) {
  __shared__ alignas(16) uint16_t Wlds[16 * 64 * 8];
  const int tid = threadIdx.x;
  const int g0 = blockIdx.x * 16;
  for (int f = tid; f < 16 * 64; f += 512) {
    const int kt = f >> 6, fl = f & 63;
    const int g = g0 + (fl & 15);
    const int k = kt * 32 + ((fl >> 4) << 3);
    const float* s = Wenc + (size_t)g * kNP + k;
    uint16_t* d = Wlds + f * 8;
#pragma unroll
    for (int j = 0; j < 8; j++) d[j] = f2bf(s[j]);
  }
  __syncthreads();
  const int wave = tid >> 6;
  const int lane = tid & 63;
  const int mrow = wave * 16 + (lane & 15);
  const float* arow = p0 + (size_t)mrow * kNP + ((lane >> 4) << 3);
  f32x4 acc = {0.f, 0.f, 0.f, 0.f};
#pragma unroll
  for (int kt = 0; kt < 16; kt++) {
    const float* ap = arow + kt * 32;
    bf16x8 a;
#pragma unroll
    for (int j = 0; j < 8; j++) a[j] = (short)f2bf(ap[j]);
    bf16x8 b = *(const bf16x8*)(Wlds + (kt * 64 + lane) * 8);
    acc = __builtin_amdgcn_mfma_f32_16x16x32_bf16(a, b, acc, 0, 0, 0);
  }
  const int gcol = g0 + (lane & 15);
  const int rbase = wave * 16 + ((lane >> 4) << 2);
#pragma unroll
  for (int r = 0; r < 4; r++) {
    H0S[a_img_off(rbase + r, gcol)] = f2bf(acc[r]);
  }
}

// ---- persistent RNN loop: round-6 verified protocol (frozen) ----
__global__ __launch_bounds__(512, 2) void rnn_loop_kernel(const uint16_t* __restrict__ WhS,
                                                          const uint16_t* __restrict__ H0S,
                                                          uint16_t* __restrict__ Gsw,
                                                          float* __restrict__ Part,
                                                          const float* __restrict__ v,
                                                          const float* __restrict__ Wih,
                                                          int* __restrict__ flags) {
  extern __shared__ uint16_t wlds[];  // 131072 B
  const int tid = threadIdx.x;
  const int wave = tid >> 6, lane = tid & 63;
  const int bid = blockIdx.x;
  const int xcd = bid & 7;                 // dispatch round-robin heuristic (perf-only)
  const int gt = xcd * 4 + (bid >> 6);     // all 8 ks-blocks of gt on one XCD
  const int ks = (bid >> 3) & 7;
  const int mg = wave >> 1, ng = wave & 1;

  int* pcnt = flags;            // [gt] stride 32
  int* hcnt = flags + 32 * 32;  // [gt] stride 32

  // one-time: W tile (row gt, chunks ks*4..+3) -> LDS, linear copy
  {
    const uint16_t* src = WhS + ((size_t)gt << 19) + ((size_t)(ks * 4) << 14);
#pragma unroll
    for (int i = 0; i < 16; i++) {
      const int j = wave * 16 + i;
      gl2lds16(src + (j << 9) + (lane << 3), (void*)(wlds + (j << 9)));
    }
  }
  __syncthreads();

  // reduce-phase coords: 16 rows x 128 g per block, 4 g per thread
  const int rbred = ks * 16 + (tid >> 5);  // batch row
  const int gl = (tid & 31) << 2;          // local g 0..124
  const int gg = gt * 128 + gl;            // global g
  float* myPart = Part + (((size_t)(gt * 8 + ks)) << 14);

  // loop-invariant Wih rows for this thread's 4 g (register-level micro-opt)
  const float4 w0 = *(const float4*)(Wih + gg * 2);
  const float4 w1 = *(const float4*)(Wih + gg * 2 + 4);

  for (int t = 0; t < kT; t++) {
    // wait: h(t-1) chunks 4ks..4ks+3 ready; hcnt[gt] doubles as Part WAR gate
    if (t > 0) {
      const int target = 8 * t;
      if (tid < 5) {
        int* f = (tid < 4) ? (hcnt + ((ks * 4 + tid) << 5)) : (hcnt + (gt << 5));
        while (__hip_atomic_load(f, __ATOMIC_RELAXED, __HIP_MEMORY_SCOPE_AGENT) < target)
          __builtin_amdgcn_s_sleep(1);
      }
      __builtin_amdgcn_fence(__ATOMIC_ACQUIRE, "workgroup");  // compiler order; no cache op
      __syncthreads();
    }

    // prefetch v(t) for the reduce phase (latency hides under mm)
    const float v0 = v[(rbred * kT + t) * 2 + 0];
    const float v1 = v[(rbred * kT + t) * 2 + 1];

    const uint16_t* Aimg = (t == 0) ? H0S : (Gsw + (((size_t)(t - 1)) << 19));
    f32x4 acc[2][4];
#pragma unroll
    for (int i = 0; i < 2; i++)
#pragma unroll
      for (int j = 0; j < 4; j++) acc[i][j] = (f32x4){0.f, 0.f, 0.f, 0.f};

#pragma unroll
    for (int kc = 0; kc < 4; kc++) {
      const uint16_t* Ac = Aimg + ((size_t)(ks * 4 + kc) << 14);
      bf16x8 a[2][4];
#pragma unroll
      for (int mi = 0; mi < 2; mi++)
#pragma unroll
        for (int ktl = 0; ktl < 4; ktl++)
          a[mi][ktl] = *(const bf16x8*)(Ac + ((((mg * 2 + mi) * 4 + ktl) * 64 + lane) << 3));
#pragma unroll
      for (int ktl = 0; ktl < 4; ktl++) {
#pragma unroll
        for (int nt = 0; nt < 4; nt++) {
          bf16x8 b = *(const bf16x8*)(wlds + (kc << 14) +
                                      ((((ng * 4 + nt) * 4 + ktl) * 64 + lane) << 3));
          acc[0][nt] = __builtin_amdgcn_mfma_f32_16x16x32_bf16(a[0][ktl], b, acc[0][nt], 0, 0, 0);
          acc[1][nt] = __builtin_amdgcn_mfma_f32_16x16x32_bf16(a[1][ktl], b, acc[1][nt], 0, 0, 0);
        }
      }
    }
    // Part write: NORMAL stores -> XCD-shared L2 (round-6 verified)
    {
      const int gcol0 = (ng << 6);
      const int rbase = (mg << 5) + ((lane >> 4) << 2);
#pragma unroll
      for (int mi = 0; mi < 2; mi++)
#pragma unroll
        for (int nt = 0; nt < 4; nt++)
#pragma unroll
          for (int r = 0; r < 4; r++) {
            const int b = rbase + (mi << 4) + r;
            const int g = gcol0 + (nt << 4) + (lane & 15);
            myPart[(b << 7) + g] = acc[mi][nt][r];
          }
    }
    asm volatile("s_waitcnt vmcnt(0)" ::: "memory");  // Part committed
    __syncthreads();
    if (tid == 0) {
      // publish Part: RELAXED counter add (round-6 verified local optimum)
      __hip_atomic_fetch_add(pcnt + (gt << 5), 1, __ATOMIC_RELAXED, __HIP_MEMORY_SCOPE_AGENT);
      const int tgt = 8 * (t + 1);
      while (__hip_atomic_load(pcnt + (gt << 5), __ATOMIC_RELAXED, __HIP_MEMORY_SCOPE_AGENT) < tgt)
        __builtin_amdgcn_s_sleep(1);
      __builtin_amdgcn_fence(__ATOMIC_ACQUIRE, "workgroup");  // compiler order only
    }
    __syncthreads();

    // reduce rows [16ks..+16) over 8 slices + vin + tanh -> Gsw[t] A-image.
    // Part reads: sc0 (bypass stale L1; served by shared L2 / MALL).
    {
      const float* pb = Part + (((size_t)(gt * 8)) << 14) + (rbred << 7) + gl;
      f32x4 pv[8];
#pragma unroll
      for (int j = 0; j < 8; j++) {
        asm volatile("global_load_dwordx4 %0, %1, off sc0"
                     : "=v"(pv[j])
                     : "v"(pb + ((size_t)j << 14))
                     : "memory");
      }
      asm volatile("s_waitcnt vmcnt(0)" ::: "memory");
      __builtin_amdgcn_sched_barrier(0);  // rule #18: keep VALU below the waitcnt
      float s0 = 0.f, s1 = 0.f, s2 = 0.f, s3 = 0.f;
#pragma unroll
      for (int j = 0; j < 8; j++) {
        s0 += pv[j][0]; s1 += pv[j][1]; s2 += pv[j][2]; s3 += pv[j][3];
      }
      const uint16_t h0 = f2bf(fast_tanh(s0 + v0 * w0.x + v1 * w0.y));
      const uint16_t h1 = f2bf(fast_tanh(s1 + v0 * w0.z + v1 * w0.w));
      const uint16_t h2 = f2bf(fast_tanh(s2 + v0 * w1.x + v1 * w1.y));
      const uint16_t h3 = f2bf(fast_tanh(s3 + v0 * w1.z + v1 * w1.w));
      const uint32_t lo = (uint32_t)h0 | ((uint32_t)h1 << 16);
      const uint32_t hi = (uint32_t)h2 | ((uint32_t)h3 << 16);
      const unsigned long long uval = ((unsigned long long)hi << 32) | lo;
      uint16_t* Gt = Gsw + (((size_t)t) << 19);
      // h publish: atomic swap executes at the LLC (agent coherence point)
      __hip_atomic_exchange((unsigned long long*)(Gt + a_img_off(rbred, gg)), uval,
                            __ATOMIC_RELAXED, __HIP_MEMORY_SCOPE_AGENT);
    }
    asm volatile("s_waitcnt vmcnt(0)" ::: "memory");  // h swaps done; Part consumed
    __syncthreads();
    if (tid == 0)
      __hip_atomic_fetch_add(hcnt + (gt << 5), 1, __ATOMIC_RELAXED, __HIP_MEMORY_SCOPE_AGENT);
  }
}

// ---- fallback step kernels (used only if cooperative launch is refused) ----
__global__ __launch_bounds__(512, 4) void stepmm_kernel(const uint16_t* __restrict__ Asrc,
                                                        const uint16_t* __restrict__ WhS,
                                                        float* __restrict__ Part) {
  __shared__ alignas(16) uint16_t lds[32768];
  const int tid = threadIdx.x;
  const int wave = tid >> 6, lane = tid & 63;
  const int gt = blockIdx.x >> 3, ks = blockIdx.x & 7;
  const int mg = wave >> 1, ng = wave & 1;
  const uint16_t* Wbase = WhS + ((size_t)gt << 19);
  f32x4 acc[2][4];
#pragma unroll
  for (int i = 0; i < 2; i++)
#pragma unroll
    for (int j = 0; j < 4; j++) acc[i][j] = (f32x4){0.f, 0.f, 0.f, 0.f};

  for (int kc = 0; kc < 4; kc++) {
    const int chunk = ks * 4 + kc;
    const uint16_t* Ac = Asrc + ((size_t)chunk << 14);
    const uint16_t* Bc = Wbase + ((size_t)chunk << 14);
#pragma unroll
    for (int i = 0; i < 8; i++) {
      const int j = wave * 8 + i;
      const uint16_t* s = (j < 32) ? (Ac + (j << 9)) : (Bc + ((j - 32) << 9));
      gl2lds16(s + (lane << 3), (void*)(lds + (j << 9)));
    }
    __syncthreads();
    const uint16_t* lA = lds;
    const uint16_t* lB = lds + 16384;
#pragma unroll
    for (int ktl = 0; ktl < 4; ktl++) {
      bf16x8 a0 = *(const bf16x8*)(lA + ((((mg * 2 + 0) * 4 + ktl) * 64 + lane) << 3));
      bf16x8 a1 = *(const bf16x8*)(lA + ((((mg * 2 + 1) * 4 + ktl) * 64 + lane) << 3));
#pragma unroll
      for (int nt = 0; nt < 4; nt++) {
        bf16x8 b = *(const bf16x8*)(lB + ((((ng * 4 + nt) * 4 + ktl) * 64 + lane) << 3));
        acc[0][nt] = __builtin_amdgcn_mfma_f32_16x16x32_bf16(a0, b, acc[0][nt], 0, 0, 0);
        acc[1][nt] = __builtin_amdgcn_mfma_f32_16x16x32_bf16(a1, b, acc[1][nt], 0, 0, 0);
      }
    }
    __syncthreads();
  }
  const int g0 = (gt << 7) + (ng << 6);
  const int rb = (mg << 5) + ((lane >> 4) << 2);
#pragma unroll
  for (int mi = 0; mi < 2; mi++)
#pragma unroll
    for (int nt = 0; nt < 4; nt++)
#pragma unroll
      for (int r = 0; r < 4; r++) {
        const int b = rb + (mi << 4) + r;
        const int g = g0 + (nt << 4) + (lane & 15);
        Part[(((size_t)(ks * 128 + b)) << 12) + g] = acc[mi][nt][r];
      }
}

__global__ __launch_bounds__(256) void steptanh_kernel(const float* __restrict__ Part,
                                                       const float* __restrict__ v,
                                                       const float* __restrict__ Wih,
                                                       uint16_t* __restrict__ Gt, int t) {
  const int tg = blockIdx.x * 256 + threadIdx.x;
  const int b = tg >> 9;
  const int g0 = (tg & 511) << 3;
  float s[8];
#pragma unroll
  for (int j = 0; j < 8; j++) s[j] = 0.f;
#pragma unroll
  for (int ks = 0; ks < 8; ks++) {
    const float4* p = (const float4*)(Part + (((size_t)(ks * 128 + b)) << 12) + g0);
    const float4 x = p[0], y = p[1];
    s[0] += x.x; s[1] += x.y; s[2] += x.z; s[3] += x.w;
    s[4] += y.x; s[5] += y.y; s[6] += y.z; s[7] += y.w;
  }
  const float v0 = v[(b * kT + t) * 2 + 0];
  const float v1 = v[(b * kT + t) * 2 + 1];
  uint16_t h[8];
#pragma unroll
  for (int j = 0; j < 8; j++) {
    const int g = g0 + j;
    const float pre = s[j] + v0 * Wih[g * 2 + 0] + v1 * Wih[g * 2 + 1];
    h[j] = f2bf(fast_tanh(pre));
  }
  uint4 u;
  u.x = (uint32_t)h[0] | ((uint32_t)h[1] << 16);
  u.y = (uint32_t)h[2] | ((uint32_t)h[3] << 16);
  u.z = (uint32_t)h[4] | ((uint32_t)h[5] << 16);
  u.w = (uint32_t)h[6] | ((uint32_t)h[7] << 16);
  const size_t off = ((size_t)(((g0 >> 7) * 8 + (b >> 4)) * 4 + ((g0 >> 5) & 3)) * 64 +
                      ((g0 >> 3) & 3) * 16 + (b & 15)) * 8;
  *(uint4*)(Gt + off) = u;
}

// ---- decoder: out[b,t,p] = Gsw[t] @ WdS[pt] + bias. XCD-swizzled grid:
// slot=bid&7 (XCD), t=slot+8*(m>>2), pt=m&3 -> all 4 pt of one t share an XCD's
// L2 => Gsw[t] fetched once per XCD instead of 4x across XCDs. grid 416. ----
__global__ __launch_bounds__(512, 4) void dec_kernel(const uint16_t* __restrict__ Gsw,
                                                     const uint16_t* __restrict__ WdS,
                                                     const float* __restrict__ bd,
                                                     float* __restrict__ out) {
  __shared__ alignas(16) uint16_t lds[32768];
  const int slot = blockIdx.x & 7;
  const int m = blockIdx.x >> 3;
  const int t = slot + ((m >> 2) << 3);
  const int pt = m & 3;
  if (t >= kT) return;  // uniform per block; before any barrier
  const int tid = threadIdx.x;
  const int wave = tid >> 6, lane = tid & 63;
  const int mg = wave >> 1, ng = wave & 1;
  const uint16_t* Abase = Gsw + (size_t)t * 524288;
  const uint16_t* Bbase = WdS + (size_t)pt * 524288;
  f32x4 acc[2][4];
#pragma unroll
  for (int i = 0; i < 2; i++)
#pragma unroll
    for (int j = 0; j < 4; j++) acc[i][j] = (f32x4){0.f, 0.f, 0.f, 0.f};

  for (int chunk = 0; chunk < 32; chunk++) {
    const uint16_t* Ac = Abase + ((size_t)chunk << 14);
    const uint16_t* Bc = Bbase + ((size_t)chunk << 14);
#pragma unroll
    for (int i = 0; i < 8; i++) {
      const int j = wave * 8 + i;
      const uint16_t* s = (j < 32) ? (Ac + (j << 9)) : (Bc + ((j - 32) << 9));
      gl2lds16(s + (lane << 3), (void*)(lds + (j << 9)));
    }
    __syncthreads();
    const uint16_t* lA = lds;
    const uint16_t* lB = lds + 16384;
#pragma unroll
    for (int ktl = 0; ktl < 4; ktl++) {
      bf16x8 a0 = *(const bf16x8*)(lA + ((((mg * 2 + 0) * 4 + ktl) * 64 + lane) << 3));
      bf16x8 a1 = *(const bf16x8*)(lA + ((((mg * 2 + 1) * 4 + ktl) * 64 + lane) << 3));
#pragma unroll
      for (int nt = 0; nt < 4; nt++) {
        bf16x8 b = *(const bf16x8*)(lB + ((((ng * 4 + nt) * 4 + ktl) * 64 + lane) << 3));
        acc[0][nt] = __builtin_amdgcn_mfma_f32_16x16x32_bf16(a0, b, acc[0][nt], 0, 0, 0);
        acc[1][nt] = __builtin_amdgcn_mfma_f32_16x16x32_bf16(a1, b, acc[1][nt], 0, 0, 0);
      }
    }
    __syncthreads();
  }
  const int p0c = (pt << 7) + (ng << 6);
  const int rb = (mg << 5) + ((lane >> 4) << 2);
#pragma unroll
  for (int mi = 0; mi < 2; mi++)
#pragma unroll
    for (int nt = 0; nt < 4; nt++) {
      const int p = p0c + (nt << 4) + (lane & 15);
      const float bias = bd[p];
#pragma unroll
      for (int r = 0; r < 4; r++) {
        const int b = rb + (mi << 4) + r;
        out[((size_t)b * kT + t) * kNP + p] = acc[mi][nt][r] + bias;
      }
    }
}

extern "C" void kernel_launch(void* const* d_in, const int* in_sizes, int n_in,
                              void* d_out, int out_size, void* d_ws, size_t ws_size,
                              hipStream_t stream) {
  const float* v    = (const float*)d_in[0];
  const float* p0   = (const float*)d_in[1];
  const float* Wenc = (const float*)d_in[2];
  const float* Wih  = (const float*)d_in[3];
  const float* Whh  = (const float*)d_in[4];
  const float* Wdec = (const float*)d_in[5];
  const float* bdec = (const float*)d_in[6];
  float* out = (float*)d_out;

  uint8_t* ws = (uint8_t*)d_ws;
  uint16_t* WhS = (uint16_t*)(ws);
  uint16_t* WdS = (uint16_t*)(ws + 33554432);
  uint16_t* H0S = (uint16_t*)(ws + 37748736);
  uint16_t* Gsw = (uint16_t*)(ws + 38797312);
  float*    Part = (float*)(ws + 143654912);
  int*      flags = (int*)(ws + 160432128);

  cvt_whh_kernel<<<4096, 512, 0, stream>>>(Whh, WhS, flags);
  cvt_wdec_kernel<<<512, 512, 0, stream>>>(Wdec, WdS);
  enc_kernel<<<256, 512, 0, stream>>>(p0, Wenc, H0S);

  // persistent flag-synced RNN loop (cooperative launch for residency guarantee)
  const uint16_t* WhS_c = WhS;
  const uint16_t* H0S_c = H0S;
  void* args[7] = {(void*)&WhS_c, (void*)&H0S_c, (void*)&Gsw, (void*)&Part,
                   (void*)&v, (void*)&Wih, (void*)&flags};
  hipError_t e = hipLaunchCooperativeKernel(rnn_loop_kernel, dim3(256), dim3(512), args,
                                            (unsigned int)131072, stream);
  if (e != hipSuccess) {
    // fallback: per-step launches (round-1 path, ~1.96 ms class)
    (void)hipGetLastError();
    for (int t = 0; t < kT; t++) {
      const uint16_t* Asrc = (t == 0) ? H0S : (Gsw + (size_t)(t - 1) * 524288);
      stepmm_kernel<<<256, 512, 0, stream>>>(Asrc, WhS, Part);
      steptanh_kernel<<<256, 256, 0, stream>>>(Part, v, Wih, Gsw + (size_t)t * 524288, t);
    }
  }

  dec_kernel<<<416, 512, 0, stream>>>(Gsw, WdS, bdec, out);
}

// Round 11
// 1071.849 us; speedup vs baseline: 3.7146x; 1.0562x over previous
//
// RNN_79577154060490 — round 12: bf16 Part (halve the per-step L2->MALL Part
// stream) + coalesced cvt kernels. Loop protocol = round-6/11 verified (frozen).
// h0=p0@W_enc^T; 100x h=tanh(v@W_ih^T+h@W_hh^T); out = g@W_dec^T + b
//
// Ledger: r6 sync protocol = local optimum (r7 3430, r9 1130, r10 1078 vs 947).
// r11: loop 925us (micro-opts real), dec-swizzle neutral, total 1132.
// Round-12 (two independent, separately-attributable mechanisms):
//  * Part fp32 -> bf16: WRITE_SIZE 15MB/step is Part streaming to MALL each
//    step (capacity eviction, r9-proven). bf16 halves stream+drain+read bytes.
//    Precision: +0.0008/step rounding vs existing 0.002 bf16-h noise; 3.4x
//    absmax headroom. If absmax>0.0537: revert Part only.
//  * cvt_whh/cvt_wdec: inverted mapping (thread = linear output 16B-unit,
//    gather from W). Writes fully linear; W lines fully consumed (4 lanes per
//    128B line). Was: 16B/lane scattered at 256B stride.
// Loop protocol (frozen): W_hh LDS-resident; A plain cached; Part normal
// stores + sc0 reads; h via agent atomic-exchange (LLC); pcnt/hcnt relaxed
// counters (tid<5 wait, tid0 agents); Wih hoist; v(t) prefetch.
//
// ws layout (bytes) [unchanged; bf16 Part uses first 8MB of Part region]:
//   [0,         33554432)   WhS  bf16 [gt32][chunk32][nt8][ktl4][64][8]
//   [33554432,  37748736)   WdS  bf16 [pt4][chunk32][nt8][ktl4][64][8]
//   [37748736,  38797312)   H0S  bf16 A-image (1MB)
//   [38797312, 143654912)   Gsw  bf16 [t100] A-images (100MB)
//   [143654912,160432128)   Part region (main: bf16 [gt32][ks8][128][128])
//   [160432128,160440320)   flags int[2048] (pcnt[32] @0, hcnt[32] @+1024; stride 32)

#include <hip/hip_runtime.h>
#include <stdint.h>

namespace {
constexpr int kT = 100;
constexpr int kNG = 4096;
constexpr int kNP = 512;

__device__ __forceinline__ uint16_t f2bf(float f) {
  uint32_t u = __float_as_uint(f);
  u += 0x7FFFu + ((u >> 16) & 1u);
  return (uint16_t)(u >> 16);
}

__device__ __forceinline__ float bfbits(uint32_t lo16) {  // bf16 bits -> f32
  return __uint_as_float(lo16 << 16);
}

__device__ __forceinline__ float fast_tanh(float x) {
  float xc = fminf(fmaxf(x, -15.f), 15.f);
  float e = __expf(2.f * xc);
  return (e - 1.f) / (e + 1.f);
}

__device__ __forceinline__ void gl2lds16(const void* g, void* l) {
  __builtin_amdgcn_global_load_lds((const __attribute__((address_space(1))) unsigned int*)g,
                                   (__attribute__((address_space(3))) unsigned int*)l, 16, 0, 0);
}

// fragment-image element offsets (within one tensor)
__device__ __forceinline__ size_t a_img_off(int b, int g) {  // g = k index
  return ((size_t)(((g >> 7) * 8 + (b >> 4)) * 4 + ((g >> 5) & 3)) * 64 +
          ((g >> 3) & 3) * 16 + (b & 15)) * 8 + (g & 7);
}
}  // namespace

typedef short bf16x8 __attribute__((ext_vector_type(8)));
typedef float f32x4 __attribute__((ext_vector_type(4)));
typedef uint32_t u32x2 __attribute__((ext_vector_type(2)));

// ---- cvt W_hh fp32 [4096][4096] -> WhS B-image bf16. Coalesced: thread owns
// one linear 16B output unit; gathers 8 source floats. (+flag zero) ----
__global__ __launch_bounds__(512) void cvt_whh_kernel(const float* __restrict__ W,
                                                      uint16_t* __restrict__ WhS,
                                                      int* __restrict__ flags) {
  if (blockIdx.x == 4095) {
    for (int i = threadIdx.x; i < 2048; i += 512) flags[i] = 0;
  }
  const int u = blockIdx.x * 512 + threadIdx.x;  // 2M units of 8 elements
  const int col = u & 15, half = (u >> 4) & 3, ktl = (u >> 6) & 3;
  const int nt = (u >> 8) & 7, chunk = (u >> 11) & 31, gt = u >> 16;
  const int g = gt * 128 + nt * 16 + col;
  const int k0 = chunk * 128 + ktl * 32 + half * 8;
  const float4 x = *(const float4*)(W + (size_t)g * kNG + k0);
  const float4 y = *(const float4*)(W + (size_t)g * kNG + k0 + 4);
  uint4 o;
  o.x = (uint32_t)f2bf(x.x) | ((uint32_t)f2bf(x.y) << 16);
  o.y = (uint32_t)f2bf(x.z) | ((uint32_t)f2bf(x.w) << 16);
  o.z = (uint32_t)f2bf(y.x) | ((uint32_t)f2bf(y.y) << 16);
  o.w = (uint32_t)f2bf(y.z) | ((uint32_t)f2bf(y.w) << 16);
  *(uint4*)(WhS + (size_t)u * 8) = o;  // fully linear store
}

// ---- cvt W_dec fp32 [512][4096] -> WdS B-image bf16 (coalesced, as above) ----
__global__ __launch_bounds__(512) void cvt_wdec_kernel(const float* __restrict__ W,
                                                       uint16_t* __restrict__ WdS) {
  const int u = blockIdx.x * 512 + threadIdx.x;  // 256K units
  const int col = u & 15, half = (u >> 4) & 3, ktl = (u >> 6) & 3;
  const int nt = (u >> 8) & 7, chunk = (u >> 11) & 31, pt = u >> 16;
  const int p = pt * 128 + nt * 16 + col;
  const int k0 = chunk * 128 + ktl * 32 + half * 8;
  const float4 x = *(const float4*)(W + (size_t)p * kNG + k0);
  const float4 y = *(const float4*)(W + (size_t)p * kNG + k0 + 4);
  uint4 o;
  o.x = (uint32_t)f2bf(x.x) | ((uint32_t)f2bf(x.y) << 16);
  o.y = (uint32_t)f2bf(x.z) | ((uint32_t)f2bf(x.w) << 16);
  o.z = (uint32_t)f2bf(y.x) | ((uint32_t)f2bf(y.y) << 16);
  o.w = (uint32_t)f2bf(y.z) | ((uint32_t)f2bf(y.w) << 16);
  *(uint4*)(WdS + (size_t)u * 8) = o;
}

// ---- encoder: H0S = A-image of p0 @ Wenc^T (bf16) ----
__global__ __launch_bounds__(512, 2) void enc_kernel(const float* __restrict__ p0,
                                                     const float* __restrict__ Wenc,
                                                     uint16_t* __restrict__ H0S) {
  __shared__ alignas(16) uint16_t Wlds[16 * 64 * 8];
  const int tid = threadIdx.x;
  const int g0 = blockIdx.x * 16;
  for (int f = tid; f < 16 * 64; f += 512) {
    const int kt = f >> 6, fl = f & 63;
    const int g = g0 + (fl & 15);
    const int k = kt * 32 + ((fl >> 4) << 3);
    const float* s = Wenc + (size_t)g * kNP + k;
    uint16_t* d = Wlds + f * 8;
#pragma unroll
    for (int j = 0; j < 8; j++) d[j] = f2bf(s[j]);
  }
  __syncthreads();
  const int wave = tid >> 6;
  const int lane = tid & 63;
  const int mrow = wave * 16 + (lane & 15);
  const float* arow = p0 + (size_t)mrow * kNP + ((lane >> 4) << 3);
  f32x4 acc = {0.f, 0.f, 0.f, 0.f};
#pragma unroll
  for (int kt = 0; kt < 16; kt++) {
    const float* ap = arow + kt * 32;
    bf16x8 a;
#pragma unroll
    for (int j = 0; j < 8; j++) a[j] = (short)f2bf(ap[j]);
    bf16x8 b = *(const bf16x8*)(Wlds + (kt * 64 + lane) * 8);
    acc = __builtin_amdgcn_mfma_f32_16x16x32_bf16(a, b, acc, 0, 0, 0);
  }
  const int gcol = g0 + (lane & 15);
  const int rbase = wave * 16 + ((lane >> 4) << 2);
#pragma unroll
  for (int r = 0; r < 4; r++) {
    H0S[a_img_off(rbase + r, gcol)] = f2bf(acc[r]);
  }
}

// ---- persistent RNN loop: round-6 protocol (frozen); Part is bf16 ----
__global__ __launch_bounds__(512, 2) void rnn_loop_kernel(const uint16_t* __restrict__ WhS,
                                                          const uint16_t* __restrict__ H0S,
                                                          uint16_t* __restrict__ Gsw,
                                                          float* __restrict__ Part,
                                                          const float* __restrict__ v,
                                                          const float* __restrict__ Wih,
                                                          int* __restrict__ flags) {
  extern __shared__ uint16_t wlds[];  // 131072 B
  const int tid = threadIdx.x;
  const int wave = tid >> 6, lane = tid & 63;
  const int bid = blockIdx.x;
  const int xcd = bid & 7;                 // dispatch round-robin heuristic (perf-only)
  const int gt = xcd * 4 + (bid >> 6);     // all 8 ks-blocks of gt on one XCD
  const int ks = (bid >> 3) & 7;
  const int mg = wave >> 1, ng = wave & 1;

  int* pcnt = flags;            // [gt] stride 32
  int* hcnt = flags + 32 * 32;  // [gt] stride 32
  uint16_t* PartB = (uint16_t*)Part;  // bf16 [gt32][ks8][128][128]

  // one-time: W tile (row gt, chunks ks*4..+3) -> LDS, linear copy
  {
    const uint16_t* src = WhS + ((size_t)gt << 19) + ((size_t)(ks * 4) << 14);
#pragma unroll
    for (int i = 0; i < 16; i++) {
      const int j = wave * 16 + i;
      gl2lds16(src + (j << 9) + (lane << 3), (void*)(wlds + (j << 9)));
    }
  }
  __syncthreads();

  // reduce-phase coords: 16 rows x 128 g per block, 4 g per thread
  const int rbred = ks * 16 + (tid >> 5);  // batch row
  const int gl = (tid & 31) << 2;          // local g 0..124
  const int gg = gt * 128 + gl;            // global g
  uint16_t* myPart = PartB + (((size_t)(gt * 8 + ks)) << 14);

  // loop-invariant Wih rows for this thread's 4 g
  const float4 w0 = *(const float4*)(Wih + gg * 2);
  const float4 w1 = *(const float4*)(Wih + gg * 2 + 4);

  for (int t = 0; t < kT; t++) {
    // wait: h(t-1) chunks 4ks..4ks+3 ready; hcnt[gt] doubles as Part WAR gate
    if (t > 0) {
      const int target = 8 * t;
      if (tid < 5) {
        int* f = (tid < 4) ? (hcnt + ((ks * 4 + tid) << 5)) : (hcnt + (gt << 5));
        while (__hip_atomic_load(f, __ATOMIC_RELAXED, __HIP_MEMORY_SCOPE_AGENT) < target)
          __builtin_amdgcn_s_sleep(1);
      }
      __builtin_amdgcn_fence(__ATOMIC_ACQUIRE, "workgroup");  // compiler order; no cache op
      __syncthreads();
    }

    // prefetch v(t) for the reduce phase (latency hides under mm)
    const float v0 = v[(rbred * kT + t) * 2 + 0];
    const float v1 = v[(rbred * kT + t) * 2 + 1];

    const uint16_t* Aimg = (t == 0) ? H0S : (Gsw + (((size_t)(t - 1)) << 19));
    f32x4 acc[2][4];
#pragma unroll
    for (int i = 0; i < 2; i++)
#pragma unroll
      for (int j = 0; j < 4; j++) acc[i][j] = (f32x4){0.f, 0.f, 0.f, 0.f};

#pragma unroll
    for (int kc = 0; kc < 4; kc++) {
      const uint16_t* Ac = Aimg + ((size_t)(ks * 4 + kc) << 14);
      bf16x8 a[2][4];
#pragma unroll
      for (int mi = 0; mi < 2; mi++)
#pragma unroll
        for (int ktl = 0; ktl < 4; ktl++)
          a[mi][ktl] = *(const bf16x8*)(Ac + ((((mg * 2 + mi) * 4 + ktl) * 64 + lane) << 3));
#pragma unroll
      for (int ktl = 0; ktl < 4; ktl++) {
#pragma unroll
        for (int nt = 0; nt < 4; nt++) {
          bf16x8 b = *(const bf16x8*)(wlds + (kc << 14) +
                                      ((((ng * 4 + nt) * 4 + ktl) * 64 + lane) << 3));
          acc[0][nt] = __builtin_amdgcn_mfma_f32_16x16x32_bf16(a[0][ktl], b, acc[0][nt], 0, 0, 0);
          acc[1][nt] = __builtin_amdgcn_mfma_f32_16x16x32_bf16(a[1][ktl], b, acc[1][nt], 0, 0, 0);
        }
      }
    }
    // Part write: bf16 normal stores -> XCD-shared L2 (half the r11 bytes)
    {
      const int gcol0 = (ng << 6);
      const int rbase = (mg << 5) + ((lane >> 4) << 2);
#pragma unroll
      for (int mi = 0; mi < 2; mi++)
#pragma unroll
        for (int nt = 0; nt < 4; nt++)
#pragma unroll
          for (int r = 0; r < 4; r++) {
            const int b = rbase + (mi << 4) + r;
            const int g = gcol0 + (nt << 4) + (lane & 15);
            myPart[(b << 7) + g] = f2bf(acc[mi][nt][r]);
          }
    }
    asm volatile("s_waitcnt vmcnt(0)" ::: "memory");  // Part committed
    __syncthreads();
    if (tid == 0) {
      // publish Part: RELAXED counter add (round-6 verified local optimum)
      __hip_atomic_fetch_add(pcnt + (gt << 5), 1, __ATOMIC_RELAXED, __HIP_MEMORY_SCOPE_AGENT);
      const int tgt = 8 * (t + 1);
      while (__hip_atomic_load(pcnt + (gt << 5), __ATOMIC_RELAXED, __HIP_MEMORY_SCOPE_AGENT) < tgt)
        __builtin_amdgcn_s_sleep(1);
      __builtin_amdgcn_fence(__ATOMIC_ACQUIRE, "workgroup");  // compiler order only
    }
    __syncthreads();

    // reduce rows [16ks..+16) over 8 slices + vin + tanh -> Gsw[t] A-image.
    // Part reads: sc0 dwordx2 (4 bf16 per slice per thread).
    {
      const uint16_t* pb = PartB + (((size_t)(gt * 8)) << 14) + (rbred << 7) + gl;
      u32x2 pv[8];
#pragma unroll
      for (int j = 0; j < 8; j++) {
        asm volatile("global_load_dwordx2 %0, %1, off sc0"
                     : "=v"(pv[j])
                     : "v"(pb + ((size_t)j << 14))
                     : "memory");
      }
      asm volatile("s_waitcnt vmcnt(0)" ::: "memory");
      __builtin_amdgcn_sched_barrier(0);  // rule #18: keep VALU below the waitcnt
      float s0 = 0.f, s1 = 0.f, s2 = 0.f, s3 = 0.f;
#pragma unroll
      for (int j = 0; j < 8; j++) {
        s0 += bfbits(pv[j][0] & 0xFFFFu);
        s1 += __uint_as_float(pv[j][0] & 0xFFFF0000u);
        s2 += bfbits(pv[j][1] & 0xFFFFu);
        s3 += __uint_as_float(pv[j][1] & 0xFFFF0000u);
      }
      const uint16_t h0 = f2bf(fast_tanh(s0 + v0 * w0.x + v1 * w0.y));
      const uint16_t h1 = f2bf(fast_tanh(s1 + v0 * w0.z + v1 * w0.w));
      const uint16_t h2 = f2bf(fast_tanh(s2 + v0 * w1.x + v1 * w1.y));
      const uint16_t h3 = f2bf(fast_tanh(s3 + v0 * w1.z + v1 * w1.w));
      const uint32_t lo = (uint32_t)h0 | ((uint32_t)h1 << 16);
      const uint32_t hi = (uint32_t)h2 | ((uint32_t)h3 << 16);
      const unsigned long long uval = ((unsigned long long)hi << 32) | lo;
      uint16_t* Gt = Gsw + (((size_t)t) << 19);
      // h publish: atomic swap executes at the LLC (agent coherence point)
      __hip_atomic_exchange((unsigned long long*)(Gt + a_img_off(rbred, gg)), uval,
                            __ATOMIC_RELAXED, __HIP_MEMORY_SCOPE_AGENT);
    }
    asm volatile("s_waitcnt vmcnt(0)" ::: "memory");  // h swaps done; Part consumed
    __syncthreads();
    if (tid == 0)
      __hip_atomic_fetch_add(hcnt + (gt << 5), 1, __ATOMIC_RELAXED, __HIP_MEMORY_SCOPE_AGENT);
  }
}

// ---- fallback step kernels (used only if cooperative launch is refused;
//      fp32 Part layout [ks8][128][4096] in the same ws region) ----
__global__ __launch_bounds__(512, 4) void stepmm_kernel(const uint16_t* __restrict__ Asrc,
                                                        const uint16_t* __restrict__ WhS,
                                                        float* __restrict__ Part) {
  __shared__ alignas(16) uint16_t lds[32768];
  const int tid = threadIdx.x;
  const int wave = tid >> 6, lane = tid & 63;
  const int gt = blockIdx.x >> 3, ks = blockIdx.x & 7;
  const int mg = wave >> 1, ng = wave & 1;
  const uint16_t* Wbase = WhS + ((size_t)gt << 19);
  f32x4 acc[2][4];
#pragma unroll
  for (int i = 0; i < 2; i++)
#pragma unroll
    for (int j = 0; j < 4; j++) acc[i][j] = (f32x4){0.f, 0.f, 0.f, 0.f};

  for (int kc = 0; kc < 4; kc++) {
    const int chunk = ks * 4 + kc;
    const uint16_t* Ac = Asrc + ((size_t)chunk << 14);
    const uint16_t* Bc = Wbase + ((size_t)chunk << 14);
#pragma unroll
    for (int i = 0; i < 8; i++) {
      const int j = wave * 8 + i;
      const uint16_t* s = (j < 32) ? (Ac + (j << 9)) : (Bc + ((j - 32) << 9));
      gl2lds16(s + (lane << 3), (void*)(lds + (j << 9)));
    }
    __syncthreads();
    const uint16_t* lA = lds;
    const uint16_t* lB = lds + 16384;
#pragma unroll
    for (int ktl = 0; ktl < 4; ktl++) {
      bf16x8 a0 = *(const bf16x8*)(lA + ((((mg * 2 + 0) * 4 + ktl) * 64 + lane) << 3));
      bf16x8 a1 = *(const bf16x8*)(lA + ((((mg * 2 + 1) * 4 + ktl) * 64 + lane) << 3));
#pragma unroll
      for (int nt = 0; nt < 4; nt++) {
        bf16x8 b = *(const bf16x8*)(lB + ((((ng * 4 + nt) * 4 + ktl) * 64 + lane) << 3));
        acc[0][nt] = __builtin_amdgcn_mfma_f32_16x16x32_bf16(a0, b, acc[0][nt], 0, 0, 0);
        acc[1][nt] = __builtin_amdgcn_mfma_f32_16x16x32_bf16(a1, b, acc[1][nt], 0, 0, 0);
      }
    }
    __syncthreads();
  }
  const int g0 = (gt << 7) + (ng << 6);
  const int rb = (mg << 5) + ((lane >> 4) << 2);
#pragma unroll
  for (int mi = 0; mi < 2; mi++)
#pragma unroll
    for (int nt = 0; nt < 4; nt++)
#pragma unroll
      for (int r = 0; r < 4; r++) {
        const int b = rb + (mi << 4) + r;
        const int g = g0 + (nt << 4) + (lane & 15);
        Part[(((size_t)(ks * 128 + b)) << 12) + g] = acc[mi][nt][r];
      }
}

__global__ __launch_bounds__(256) void steptanh_kernel(const float* __restrict__ Part,
                                                       const float* __restrict__ v,
                                                       const float* __restrict__ Wih,
                                                       uint16_t* __restrict__ Gt, int t) {
  const int tg = blockIdx.x * 256 + threadIdx.x;
  const int b = tg >> 9;
  const int g0 = (tg & 511) << 3;
  float s[8];
#pragma unroll
  for (int j = 0; j < 8; j++) s[j] = 0.f;
#pragma unroll
  for (int ks = 0; ks < 8; ks++) {
    const float4* p = (const float4*)(Part + (((size_t)(ks * 128 + b)) << 12) + g0);
    const float4 x = p[0], y = p[1];
    s[0] += x.x; s[1] += x.y; s[2] += x.z; s[3] += x.w;
    s[4] += y.x; s[5] += y.y; s[6] += y.z; s[7] += y.w;
  }
  const float v0 = v[(b * kT + t) * 2 + 0];
  const float v1 = v[(b * kT + t) * 2 + 1];
  uint16_t h[8];
#pragma unroll
  for (int j = 0; j < 8; j++) {
    const int g = g0 + j;
    const float pre = s[j] + v0 * Wih[g * 2 + 0] + v1 * Wih[g * 2 + 1];
    h[j] = f2bf(fast_tanh(pre));
  }
  uint4 u;
  u.x = (uint32_t)h[0] | ((uint32_t)h[1] << 16);
  u.y = (uint32_t)h[2] | ((uint32_t)h[3] << 16);
  u.z = (uint32_t)h[4] | ((uint32_t)h[5] << 16);
  u.w = (uint32_t)h[6] | ((uint32_t)h[7] << 16);
  const size_t off = ((size_t)(((g0 >> 7) * 8 + (b >> 4)) * 4 + ((g0 >> 5) & 3)) * 64 +
                      ((g0 >> 3) & 3) * 16 + (b & 15)) * 8;
  *(uint4*)(Gt + off) = u;
}

// ---- decoder: out[b,t,p] = Gsw[t] @ WdS[pt] + bias. XCD-swizzled grid (r11,
// neutral but harmless): slot=bid&7, t=slot+8*(m>>2), pt=m&3; grid 416. ----
__global__ __launch_bounds__(512, 4) void dec_kernel(const uint16_t* __restrict__ Gsw,
                                                     const uint16_t* __restrict__ WdS,
                                                     const float* __restrict__ bd,
                                                     float* __restrict__ out) {
  __shared__ alignas(16) uint16_t lds[32768];
  const int slot = blockIdx.x & 7;
  const int m = blockIdx.x >> 3;
  const int t = slot + ((m >> 2) << 3);
  const int pt = m & 3;
  if (t >= kT) return;  // uniform per block; before any barrier
  const int tid = threadIdx.x;
  const int wave = tid >> 6, lane = tid & 63;
  const int mg = wave >> 1, ng = wave & 1;
  const uint16_t* Abase = Gsw + (size_t)t * 524288;
  const uint16_t* Bbase = WdS + (size_t)pt * 524288;
  f32x4 acc[2][4];
#pragma unroll
  for (int i = 0; i < 2; i++)
#pragma unroll
    for (int j = 0; j < 4; j++) acc[i][j] = (f32x4){0.f, 0.f, 0.f, 0.f};

  for (int chunk = 0; chunk < 32; chunk++) {
    const uint16_t* Ac = Abase + ((size_t)chunk << 14);
    const uint16_t* Bc = Bbase + ((size_t)chunk << 14);
#pragma unroll
    for (int i = 0; i < 8; i++) {
      const int j = wave * 8 + i;
      const uint16_t* s = (j < 32) ? (Ac + (j << 9)) : (Bc + ((j - 32) << 9));
      gl2lds16(s + (lane << 3), (void*)(lds + (j << 9)));
    }
    __syncthreads();
    const uint16_t* lA = lds;
    const uint16_t* lB = lds + 16384;
#pragma unroll
    for (int ktl = 0; ktl < 4; ktl++) {
      bf16x8 a0 = *(const bf16x8*)(lA + ((((mg * 2 + 0) * 4 + ktl) * 64 + lane) << 3));
      bf16x8 a1 = *(const bf16x8*)(lA + ((((mg * 2 + 1) * 4 + ktl) * 64 + lane) << 3));
#pragma unroll
      for (int nt = 0; nt < 4; nt++) {
        bf16x8 b = *(const bf16x8*)(lB + ((((ng * 4 + nt) * 4 + ktl) * 64 + lane) << 3));
        acc[0][nt] = __builtin_amdgcn_mfma_f32_16x16x32_bf16(a0, b, acc[0][nt], 0, 0, 0);
        acc[1][nt] = __builtin_amdgcn_mfma_f32_16x16x32_bf16(a1, b, acc[1][nt], 0, 0, 0);
      }
    }
    __syncthreads();
  }
  const int p0c = (pt << 7) + (ng << 6);
  const int rb = (mg << 5) + ((lane >> 4) << 2);
#pragma unroll
  for (int mi = 0; mi < 2; mi++)
#pragma unroll
    for (int nt = 0; nt < 4; nt++) {
      const int p = p0c + (nt << 4) + (lane & 15);
      const float bias = bd[p];
#pragma unroll
      for (int r = 0; r < 4; r++) {
        const int b = rb + (mi << 4) + r;
        out[((size_t)b * kT + t) * kNP + p] = acc[mi][nt][r] + bias;
      }
    }
}

extern "C" void kernel_launch(void* const* d_in, const int* in_sizes, int n_in,
                              void* d_out, int out_size, void* d_ws, size_t ws_size,
                              hipStream_t stream) {
  const float* v    = (const float*)d_in[0];
  const float* p0   = (const float*)d_in[1];
  const float* Wenc = (const float*)d_in[2];
  const float* Wih  = (const float*)d_in[3];
  const float* Whh  = (const float*)d_in[4];
  const float* Wdec = (const float*)d_in[5];
  const float* bdec = (const float*)d_in[6];
  float* out = (float*)d_out;

  uint8_t* ws = (uint8_t*)d_ws;
  uint16_t* WhS = (uint16_t*)(ws);
  uint16_t* WdS = (uint16_t*)(ws + 33554432);
  uint16_t* H0S = (uint16_t*)(ws + 37748736);
  uint16_t* Gsw = (uint16_t*)(ws + 38797312);
  float*    Part = (float*)(ws + 143654912);
  int*      flags = (int*)(ws + 160432128);

  cvt_whh_kernel<<<4096, 512, 0, stream>>>(Whh, WhS, flags);
  cvt_wdec_kernel<<<512, 512, 0, stream>>>(Wdec, WdS);
  enc_kernel<<<256, 512, 0, stream>>>(p0, Wenc, H0S);

  // persistent flag-synced RNN loop (cooperative launch for residency guarantee)
  const uint16_t* WhS_c = WhS;
  const uint16_t* H0S_c = H0S;
  void* args[7] = {(void*)&WhS_c, (void*)&H0S_c, (void*)&Gsw, (void*)&Part,
                   (void*)&v, (void*)&Wih, (void*)&flags};
  hipError_t e = hipLaunchCooperativeKernel(rnn_loop_kernel, dim3(256), dim3(512), args,
                                            (unsigned int)131072, stream);
  if (e != hipSuccess) {
    // fallback: per-step launches (round-1 path, ~1.96 ms class)
    (void)hipGetLastError();
    for (int t = 0; t < kT; t++) {
      const uint16_t* Asrc = (t == 0) ? H0S : (Gsw + (size_t)(t - 1) * 524288);
      stepmm_kernel<<<256, 512, 0, stream>>>(Asrc, WhS, Part);
      steptanh_kernel<<<256, 256, 0, stream>>>(Part, v, Wih, Gsw + (size_t)t * 524288, t);
    }
  }

  dec_kernel<<<416, 512, 0, stream>>>(Gsw, WdS, bdec, out);
}

// Round 12
// 1054.441 us; speedup vs baseline: 3.7759x; 1.0165x over previous
//
// RNN_79577154060490 — round 13: fold W_hh conversion into the loop's one-time
// LDS stage (delete cvt_whh dispatch + 32MB WhS round trip). Loop protocol =
// round-6/11/12 verified (frozen). h0=p0@W_enc^T; 100x h=tanh(v@W_ih^T+h@W_hh^T);
// out = g@W_dec^T + b
//
// Ledger: r6 sync = local optimum (r7 3430, r9 1130, r10 1078 vs 947); r11
// micro-opts -22us; r12 bf16 Part: WRITE 1.53GB->0.146GB (Part now L2-resident)
// but loop only -13us => loop is RENDEZVOUS-LATENCY-bound (~9.1us/step, ~2 LLC
// rendezvous + h-atomic drain per step). Data-path and sync levers exhausted.
// Round-13 (one mechanism, prologue): rnn_loop converts its own 256KB fp32
// Whh slice -> B-image bf16 -> LDS at startup (coalesced: wave reads 2KB
// contiguous). cvt_whh kernel + WhS traffic removed from main path (kept for
// the non-coop fallback only). Flag zeroing moved to cvt_wdec (block 511).
//
// ws layout (bytes) [WhS region now fallback-only]:
//   [0,         33554432)   WhS  bf16 (fallback only)
//   [33554432,  37748736)   WdS  bf16 [pt4][chunk32][nt8][ktl4][64][8]
//   [37748736,  38797312)   H0S  bf16 A-image (1MB)
//   [38797312, 143654912)   Gsw  bf16 [t100] A-images (100MB)
//   [143654912,160432128)   Part region (main: bf16 [gt32][ks8][128][128])
//   [160432128,160440320)   flags int[2048] (pcnt[32] @0, hcnt[32] @+1024; stride 32)

#include <hip/hip_runtime.h>
#include <stdint.h>

namespace {
constexpr int kT = 100;
constexpr int kNG = 4096;
constexpr int kNP = 512;

__device__ __forceinline__ uint16_t f2bf(float f) {
  uint32_t u = __float_as_uint(f);
  u += 0x7FFFu + ((u >> 16) & 1u);
  return (uint16_t)(u >> 16);
}

__device__ __forceinline__ float bfbits(uint32_t lo16) {  // bf16 bits -> f32
  return __uint_as_float(lo16 << 16);
}

__device__ __forceinline__ float fast_tanh(float x) {
  float xc = fminf(fmaxf(x, -15.f), 15.f);
  float e = __expf(2.f * xc);
  return (e - 1.f) / (e + 1.f);
}

__device__ __forceinline__ void gl2lds16(const void* g, void* l) {
  __builtin_amdgcn_global_load_lds((const __attribute__((address_space(1))) unsigned int*)g,
                                   (__attribute__((address_space(3))) unsigned int*)l, 16, 0, 0);
}

// fragment-image element offsets (within one tensor)
__device__ __forceinline__ size_t a_img_off(int b, int g) {  // g = k index
  return ((size_t)(((g >> 7) * 8 + (b >> 4)) * 4 + ((g >> 5) & 3)) * 64 +
          ((g >> 3) & 3) * 16 + (b & 15)) * 8 + (g & 7);
}
}  // namespace

typedef short bf16x8 __attribute__((ext_vector_type(8)));
typedef float f32x4 __attribute__((ext_vector_type(4)));
typedef uint32_t u32x2 __attribute__((ext_vector_type(2)));

// ---- (fallback only) cvt W_hh fp32 -> WhS B-image bf16, coalesced ----
__global__ __launch_bounds__(512) void cvt_whh_kernel(const float* __restrict__ W,
                                                      uint16_t* __restrict__ WhS) {
  const int u = blockIdx.x * 512 + threadIdx.x;  // 2M units of 8 elements
  const int col = u & 15, half = (u >> 4) & 3, ktl = (u >> 6) & 3;
  const int nt = (u >> 8) & 7, chunk = (u >> 11) & 31, gt = u >> 16;
  const int g = gt * 128 + nt * 16 + col;
  const int k0 = chunk * 128 + ktl * 32 + half * 8;
  const float4 x = *(const float4*)(W + (size_t)g * kNG + k0);
  const float4 y = *(const float4*)(W + (size_t)g * kNG + k0 + 4);
  uint4 o;
  o.x = (uint32_t)f2bf(x.x) | ((uint32_t)f2bf(x.y) << 16);
  o.y = (uint32_t)f2bf(x.z) | ((uint32_t)f2bf(x.w) << 16);
  o.z = (uint32_t)f2bf(y.x) | ((uint32_t)f2bf(y.y) << 16);
  o.w = (uint32_t)f2bf(y.z) | ((uint32_t)f2bf(y.w) << 16);
  *(uint4*)(WhS + (size_t)u * 8) = o;  // fully linear store
}

// ---- cvt W_dec fp32 [512][4096] -> WdS B-image bf16 (coalesced) + flag zero ----
__global__ __launch_bounds__(512) void cvt_wdec_kernel(const float* __restrict__ W,
                                                       uint16_t* __restrict__ WdS,
                                                       int* __restrict__ flags) {
  if (blockIdx.x == 511) {
    for (int i = threadIdx.x; i < 2048; i += 512) flags[i] = 0;
  }
  const int u = blockIdx.x * 512 + threadIdx.x;  // 256K units
  const int col = u & 15, half = (u >> 4) & 3, ktl = (u >> 6) & 3;
  const int nt = (u >> 8) & 7, chunk = (u >> 11) & 31, pt = u >> 16;
  const int p = pt * 128 + nt * 16 + col;
  const int k0 = chunk * 128 + ktl * 32 + half * 8;
  const float4 x = *(const float4*)(W + (size_t)p * kNG + k0);
  const float4 y = *(const float4*)(W + (size_t)p * kNG + k0 + 4);
  uint4 o;
  o.x = (uint32_t)f2bf(x.x) | ((uint32_t)f2bf(x.y) << 16);
  o.y = (uint32_t)f2bf(x.z) | ((uint32_t)f2bf(x.w) << 16);
  o.z = (uint32_t)f2bf(y.x) | ((uint32_t)f2bf(y.y) << 16);
  o.w = (uint32_t)f2bf(y.z) | ((uint32_t)f2bf(y.w) << 16);
  *(uint4*)(WdS + (size_t)u * 8) = o;
}

// ---- encoder: H0S = A-image of p0 @ Wenc^T (bf16) ----
__global__ __launch_bounds__(512, 2) void enc_kernel(const float* __restrict__ p0,
                                                     const float* __restrict__ Wenc,
                                                     uint16_t* __restrict__ H0S) {
  __shared__ alignas(16) uint16_t Wlds[16 * 64 * 8];
  const int tid = threadIdx.x;
  const int g0 = blockIdx.x * 16;
  for (int f = tid; f < 16 * 64; f += 512) {
    const int kt = f >> 6, fl = f & 63;
    const int g = g0 + (fl & 15);
    const int k = kt * 32 + ((fl >> 4) << 3);
    const float* s = Wenc + (size_t)g * kNP + k;
    uint16_t* d = Wlds + f * 8;
#pragma unroll
    for (int j = 0; j < 8; j++) d[j] = f2bf(s[j]);
  }
  __syncthreads();
  const int wave = tid >> 6;
  const int lane = tid & 63;
  const int mrow = wave * 16 + (lane & 15);
  const float* arow = p0 + (size_t)mrow * kNP + ((lane >> 4) << 3);
  f32x4 acc = {0.f, 0.f, 0.f, 0.f};
#pragma unroll
  for (int kt = 0; kt < 16; kt++) {
    const float* ap = arow + kt * 32;
    bf16x8 a;
#pragma unroll
    for (int j = 0; j < 8; j++) a[j] = (short)f2bf(ap[j]);
    bf16x8 b = *(const bf16x8*)(Wlds + (kt * 64 + lane) * 8);
    acc = __builtin_amdgcn_mfma_f32_16x16x32_bf16(a, b, acc, 0, 0, 0);
  }
  const int gcol = g0 + (lane & 15);
  const int rbase = wave * 16 + ((lane >> 4) << 2);
#pragma unroll
  for (int r = 0; r < 4; r++) {
    H0S[a_img_off(rbase + r, gcol)] = f2bf(acc[r]);
  }
}

// ---- persistent RNN loop: round-6 protocol (frozen); W converted in-kernel ----
__global__ __launch_bounds__(512, 2) void rnn_loop_kernel(const float* __restrict__ Whh,
                                                          const uint16_t* __restrict__ H0S,
                                                          uint16_t* __restrict__ Gsw,
                                                          float* __restrict__ Part,
                                                          const float* __restrict__ v,
                                                          const float* __restrict__ Wih,
                                                          int* __restrict__ flags) {
  extern __shared__ uint16_t wlds[];  // 131072 B
  const int tid = threadIdx.x;
  const int wave = tid >> 6, lane = tid & 63;
  const int bid = blockIdx.x;
  const int xcd = bid & 7;                 // dispatch round-robin heuristic (perf-only)
  const int gt = xcd * 4 + (bid >> 6);     // all 8 ks-blocks of gt on one XCD
  const int ks = (bid >> 3) & 7;
  const int mg = wave >> 1, ng = wave & 1;

  int* pcnt = flags;            // [gt] stride 32
  int* hcnt = flags + 32 * 32;  // [gt] stride 32
  uint16_t* PartB = (uint16_t*)Part;  // bf16 [gt32][ks8][128][128]

  // one-time: convert this block's fp32 W slice (rows gt*128..+128, k
  // ks*512..+512) directly into the LDS B-image. Wave reads 2KB contiguous.
  {
    const float* wsrc = Whh + (size_t)(gt * 128) * kNG + ks * 512;
#pragma unroll
    for (int i = 0; i < 16; i++) {
      const int u = (i << 9) + tid;  // 0..8191 units of 8 floats
      const int g = u >> 6, ku = u & 63;
      const float* s = wsrc + (size_t)g * kNG + (ku << 3);
      const float4 x = *(const float4*)(s);
      const float4 y = *(const float4*)(s + 4);
      // chunk_local=ku>>4, ktl=(ku>>2)&3, half=ku&3, nt=g>>4, col=g&15
      const int lu = (((((ku >> 4) << 3) + (g >> 4)) << 2) + ((ku >> 2) & 3)) * 64 +
                     ((ku & 3) << 4) + (g & 15);
      bf16x8 o;
      o[0] = (short)f2bf(x.x); o[1] = (short)f2bf(x.y);
      o[2] = (short)f2bf(x.z); o[3] = (short)f2bf(x.w);
      o[4] = (short)f2bf(y.x); o[5] = (short)f2bf(y.y);
      o[6] = (short)f2bf(y.z); o[7] = (short)f2bf(y.w);
      *(bf16x8*)(wlds + ((size_t)lu << 3)) = o;
    }
  }
  __syncthreads();

  // reduce-phase coords: 16 rows x 128 g per block, 4 g per thread
  const int rbred = ks * 16 + (tid >> 5);  // batch row
  const int gl = (tid & 31) << 2;          // local g 0..124
  const int gg = gt * 128 + gl;            // global g
  uint16_t* myPart = PartB + (((size_t)(gt * 8 + ks)) << 14);

  // loop-invariant Wih rows for this thread's 4 g
  const float4 w0 = *(const float4*)(Wih + gg * 2);
  const float4 w1 = *(const float4*)(Wih + gg * 2 + 4);

  for (int t = 0; t < kT; t++) {
    // wait: h(t-1) chunks 4ks..4ks+3 ready; hcnt[gt] doubles as Part WAR gate
    if (t > 0) {
      const int target = 8 * t;
      if (tid < 5) {
        int* f = (tid < 4) ? (hcnt + ((ks * 4 + tid) << 5)) : (hcnt + (gt << 5));
        while (__hip_atomic_load(f, __ATOMIC_RELAXED, __HIP_MEMORY_SCOPE_AGENT) < target)
          __builtin_amdgcn_s_sleep(1);
      }
      __builtin_amdgcn_fence(__ATOMIC_ACQUIRE, "workgroup");  // compiler order; no cache op
      __syncthreads();
    }

    // prefetch v(t) for the reduce phase (latency hides under mm)
    const float v0 = v[(rbred * kT + t) * 2 + 0];
    const float v1 = v[(rbred * kT + t) * 2 + 1];

    const uint16_t* Aimg = (t == 0) ? H0S : (Gsw + (((size_t)(t - 1)) << 19));
    f32x4 acc[2][4];
#pragma unroll
    for (int i = 0; i < 2; i++)
#pragma unroll
      for (int j = 0; j < 4; j++) acc[i][j] = (f32x4){0.f, 0.f, 0.f, 0.f};

#pragma unroll
    for (int kc = 0; kc < 4; kc++) {
      const uint16_t* Ac = Aimg + ((size_t)(ks * 4 + kc) << 14);
      bf16x8 a[2][4];
#pragma unroll
      for (int mi = 0; mi < 2; mi++)
#pragma unroll
        for (int ktl = 0; ktl < 4; ktl++)
          a[mi][ktl] = *(const bf16x8*)(Ac + ((((mg * 2 + mi) * 4 + ktl) * 64 + lane) << 3));
#pragma unroll
      for (int ktl = 0; ktl < 4; ktl++) {
#pragma unroll
        for (int nt = 0; nt < 4; nt++) {
          bf16x8 b = *(const bf16x8*)(wlds + (kc << 14) +
                                      ((((ng * 4 + nt) * 4 + ktl) * 64 + lane) << 3));
          acc[0][nt] = __builtin_amdgcn_mfma_f32_16x16x32_bf16(a[0][ktl], b, acc[0][nt], 0, 0, 0);
          acc[1][nt] = __builtin_amdgcn_mfma_f32_16x16x32_bf16(a[1][ktl], b, acc[1][nt], 0, 0, 0);
        }
      }
    }
    // Part write: bf16 normal stores -> XCD-shared L2 (L2-resident, r12)
    {
      const int gcol0 = (ng << 6);
      const int rbase = (mg << 5) + ((lane >> 4) << 2);
#pragma unroll
      for (int mi = 0; mi < 2; mi++)
#pragma unroll
        for (int nt = 0; nt < 4; nt++)
#pragma unroll
          for (int r = 0; r < 4; r++) {
            const int b = rbase + (mi << 4) + r;
            const int g = gcol0 + (nt << 4) + (lane & 15);
            myPart[(b << 7) + g] = f2bf(acc[mi][nt][r]);
          }
    }
    asm volatile("s_waitcnt vmcnt(0)" ::: "memory");  // Part committed
    __syncthreads();
    if (tid == 0) {
      // publish Part: RELAXED counter add (round-6 verified local optimum)
      __hip_atomic_fetch_add(pcnt + (gt << 5), 1, __ATOMIC_RELAXED, __HIP_MEMORY_SCOPE_AGENT);
      const int tgt = 8 * (t + 1);
      while (__hip_atomic_load(pcnt + (gt << 5), __ATOMIC_RELAXED, __HIP_MEMORY_SCOPE_AGENT) < tgt)
        __builtin_amdgcn_s_sleep(1);
      __builtin_amdgcn_fence(__ATOMIC_ACQUIRE, "workgroup");  // compiler order only
    }
    __syncthreads();

    // reduce rows [16ks..+16) over 8 slices + vin + tanh -> Gsw[t] A-image.
    // Part reads: sc0 dwordx2 (4 bf16 per slice per thread).
    {
      const uint16_t* pb = PartB + (((size_t)(gt * 8)) << 14) + (rbred << 7) + gl;
      u32x2 pv[8];
#pragma unroll
      for (int j = 0; j < 8; j++) {
        asm volatile("global_load_dwordx2 %0, %1, off sc0"
                     : "=v"(pv[j])
                     : "v"(pb + ((size_t)j << 14))
                     : "memory");
      }
      asm volatile("s_waitcnt vmcnt(0)" ::: "memory");
      __builtin_amdgcn_sched_barrier(0);  // rule #18: keep VALU below the waitcnt
      float s0 = 0.f, s1 = 0.f, s2 = 0.f, s3 = 0.f;
#pragma unroll
      for (int j = 0; j < 8; j++) {
        s0 += bfbits(pv[j][0] & 0xFFFFu);
        s1 += __uint_as_float(pv[j][0] & 0xFFFF0000u);
        s2 += bfbits(pv[j][1] & 0xFFFFu);
        s3 += __uint_as_float(pv[j][1] & 0xFFFF0000u);
      }
      const uint16_t h0 = f2bf(fast_tanh(s0 + v0 * w0.x + v1 * w0.y));
      const uint16_t h1 = f2bf(fast_tanh(s1 + v0 * w0.z + v1 * w0.w));
      const uint16_t h2 = f2bf(fast_tanh(s2 + v0 * w1.x + v1 * w1.y));
      const uint16_t h3 = f2bf(fast_tanh(s3 + v0 * w1.z + v1 * w1.w));
      const uint32_t lo = (uint32_t)h0 | ((uint32_t)h1 << 16);
      const uint32_t hi = (uint32_t)h2 | ((uint32_t)h3 << 16);
      const unsigned long long uval = ((unsigned long long)hi << 32) | lo;
      uint16_t* Gt = Gsw + (((size_t)t) << 19);
      // h publish: atomic swap executes at the LLC (agent coherence point)
      __hip_atomic_exchange((unsigned long long*)(Gt + a_img_off(rbred, gg)), uval,
                            __ATOMIC_RELAXED, __HIP_MEMORY_SCOPE_AGENT);
    }
    asm volatile("s_waitcnt vmcnt(0)" ::: "memory");  // h swaps done; Part consumed
    __syncthreads();
    if (tid == 0)
      __hip_atomic_fetch_add(hcnt + (gt << 5), 1, __ATOMIC_RELAXED, __HIP_MEMORY_SCOPE_AGENT);
  }
}

// ---- fallback step kernels (used only if cooperative launch is refused;
//      fp32 Part layout [ks8][128][4096] in the same ws region) ----
__global__ __launch_bounds__(512, 4) void stepmm_kernel(const uint16_t* __restrict__ Asrc,
                                                        const uint16_t* __restrict__ WhS,
                                                        float* __restrict__ Part) {
  __shared__ alignas(16) uint16_t lds[32768];
  const int tid = threadIdx.x;
  const int wave = tid >> 6, lane = tid & 63;
  const int gt = blockIdx.x >> 3, ks = blockIdx.x & 7;
  const int mg = wave >> 1, ng = wave & 1;
  const uint16_t* Wbase = WhS + ((size_t)gt << 19);
  f32x4 acc[2][4];
#pragma unroll
  for (int i = 0; i < 2; i++)
#pragma unroll
    for (int j = 0; j < 4; j++) acc[i][j] = (f32x4){0.f, 0.f, 0.f, 0.f};

  for (int kc = 0; kc < 4; kc++) {
    const int chunk = ks * 4 + kc;
    const uint16_t* Ac = Asrc + ((size_t)chunk << 14);
    const uint16_t* Bc = Wbase + ((size_t)chunk << 14);
#pragma unroll
    for (int i = 0; i < 8; i++) {
      const int j = wave * 8 + i;
      const uint16_t* s = (j < 32) ? (Ac + (j << 9)) : (Bc + ((j - 32) << 9));
      gl2lds16(s + (lane << 3), (void*)(lds + (j << 9)));
    }
    __syncthreads();
    const uint16_t* lA = lds;
    const uint16_t* lB = lds + 16384;
#pragma unroll
    for (int ktl = 0; ktl < 4; ktl++) {
      bf16x8 a0 = *(const bf16x8*)(lA + ((((mg * 2 + 0) * 4 + ktl) * 64 + lane) << 3));
      bf16x8 a1 = *(const bf16x8*)(lA + ((((mg * 2 + 1) * 4 + ktl) * 64 + lane) << 3));
#pragma unroll
      for (int nt = 0; nt < 4; nt++) {
        bf16x8 b = *(const bf16x8*)(lB + ((((ng * 4 + nt) * 4 + ktl) * 64 + lane) << 3));
        acc[0][nt] = __builtin_amdgcn_mfma_f32_16x16x32_bf16(a0, b, acc[0][nt], 0, 0, 0);
        acc[1][nt] = __builtin_amdgcn_mfma_f32_16x16x32_bf16(a1, b, acc[1][nt], 0, 0, 0);
      }
    }
    __syncthreads();
  }
  const int g0 = (gt << 7) + (ng << 6);
  const int rb = (mg << 5) + ((lane >> 4) << 2);
#pragma unroll
  for (int mi = 0; mi < 2; mi++)
#pragma unroll
    for (int nt = 0; nt < 4; nt++)
#pragma unroll
      for (int r = 0; r < 4; r++) {
        const int b = rb + (mi << 4) + r;
        const int g = g0 + (nt << 4) + (lane & 15);
        Part[(((size_t)(ks * 128 + b)) << 12) + g] = acc[mi][nt][r];
      }
}

__global__ __launch_bounds__(256) void steptanh_kernel(const float* __restrict__ Part,
                                                       const float* __restrict__ v,
                                                       const float* __restrict__ Wih,
                                                       uint16_t* __restrict__ Gt, int t) {
  const int tg = blockIdx.x * 256 + threadIdx.x;
  const int b = tg >> 9;
  const int g0 = (tg & 511) << 3;
  float s[8];
#pragma unroll
  for (int j = 0; j < 8; j++) s[j] = 0.f;
#pragma unroll
  for (int ks = 0; ks < 8; ks++) {
    const float4* p = (const float4*)(Part + (((size_t)(ks * 128 + b)) << 12) + g0);
    const float4 x = p[0], y = p[1];
    s[0] += x.x; s[1] += x.y; s[2] += x.z; s[3] += x.w;
    s[4] += y.x; s[5] += y.y; s[6] += y.z; s[7] += y.w;
  }
  const float v0 = v[(b * kT + t) * 2 + 0];
  const float v1 = v[(b * kT + t) * 2 + 1];
  uint16_t h[8];
#pragma unroll
  for (int j = 0; j < 8; j++) {
    const int g = g0 + j;
    const float pre = s[j] + v0 * Wih[g * 2 + 0] + v1 * Wih[g * 2 + 1];
    h[j] = f2bf(fast_tanh(pre));
  }
  uint4 u;
  u.x = (uint32_t)h[0] | ((uint32_t)h[1] << 16);
  u.y = (uint32_t)h[2] | ((uint32_t)h[3] << 16);
  u.z = (uint32_t)h[4] | ((uint32_t)h[5] << 16);
  u.w = (uint32_t)h[6] | ((uint32_t)h[7] << 16);
  const size_t off = ((size_t)(((g0 >> 7) * 8 + (b >> 4)) * 4 + ((g0 >> 5) & 3)) * 64 +
                      ((g0 >> 3) & 3) * 16 + (b & 15)) * 8;
  *(uint4*)(Gt + off) = u;
}

// ---- decoder: out[b,t,p] = Gsw[t] @ WdS[pt] + bias. XCD-swizzled grid (r11,
// neutral but harmless): slot=bid&7, t=slot+8*(m>>2), pt=m&3; grid 416. ----
__global__ __launch_bounds__(512, 4) void dec_kernel(const uint16_t* __restrict__ Gsw,
                                                     const uint16_t* __restrict__ WdS,
                                                     const float* __restrict__ bd,
                                                     float* __restrict__ out) {
  __shared__ alignas(16) uint16_t lds[32768];
  const int slot = blockIdx.x & 7;
  const int m = blockIdx.x >> 3;
  const int t = slot + ((m >> 2) << 3);
  const int pt = m & 3;
  if (t >= kT) return;  // uniform per block; before any barrier
  const int tid = threadIdx.x;
  const int wave = tid >> 6, lane = tid & 63;
  const int mg = wave >> 1, ng = wave & 1;
  const uint16_t* Abase = Gsw + (size_t)t * 524288;
  const uint16_t* Bbase = WdS + (size_t)pt * 524288;
  f32x4 acc[2][4];
#pragma unroll
  for (int i = 0; i < 2; i++)
#pragma unroll
    for (int j = 0; j < 4; j++) acc[i][j] = (f32x4){0.f, 0.f, 0.f, 0.f};

  for (int chunk = 0; chunk < 32; chunk++) {
    const uint16_t* Ac = Abase + ((size_t)chunk << 14);
    const uint16_t* Bc = Bbase + ((size_t)chunk << 14);
#pragma unroll
    for (int i = 0; i < 8; i++) {
      const int j = wave * 8 + i;
      const uint16_t* s = (j < 32) ? (Ac + (j << 9)) : (Bc + ((j - 32) << 9));
      gl2lds16(s + (lane << 3), (void*)(lds + (j << 9)));
    }
    __syncthreads();
    const uint16_t* lA = lds;
    const uint16_t* lB = lds + 16384;
#pragma unroll
    for (int ktl = 0; ktl < 4; ktl++) {
      bf16x8 a0 = *(const bf16x8*)(lA + ((((mg * 2 + 0) * 4 + ktl) * 64 + lane) << 3));
      bf16x8 a1 = *(const bf16x8*)(lA + ((((mg * 2 + 1) * 4 + ktl) * 64 + lane) << 3));
#pragma unroll
      for (int nt = 0; nt < 4; nt++) {
        bf16x8 b = *(const bf16x8*)(lB + ((((ng * 4 + nt) * 4 + ktl) * 64 + lane) << 3));
        acc[0][nt] = __builtin_amdgcn_mfma_f32_16x16x32_bf16(a0, b, acc[0][nt], 0, 0, 0);
        acc[1][nt] = __builtin_amdgcn_mfma_f32_16x16x32_bf16(a1, b, acc[1][nt], 0, 0, 0);
      }
    }
    __syncthreads();
  }
  const int p0c = (pt << 7) + (ng << 6);
  const int rb = (mg << 5) + ((lane >> 4) << 2);
#pragma unroll
  for (int mi = 0; mi < 2; mi++)
#pragma unroll
    for (int nt = 0; nt < 4; nt++) {
      const int p = p0c + (nt << 4) + (lane & 15);
      const float bias = bd[p];
#pragma unroll
      for (int r = 0; r < 4; r++) {
        const int b = rb + (mi << 4) + r;
        out[((size_t)b * kT + t) * kNP + p] = acc[mi][nt][r] + bias;
      }
    }
}

extern "C" void kernel_launch(void* const* d_in, const int* in_sizes, int n_in,
                              void* d_out, int out_size, void* d_ws, size_t ws_size,
                              hipStream_t stream) {
  const float* v    = (const float*)d_in[0];
  const float* p0   = (const float*)d_in[1];
  const float* Wenc = (const float*)d_in[2];
  const float* Wih  = (const float*)d_in[3];
  const float* Whh  = (const float*)d_in[4];
  const float* Wdec = (const float*)d_in[5];
  const float* bdec = (const float*)d_in[6];
  float* out = (float*)d_out;

  uint8_t* ws = (uint8_t*)d_ws;
  uint16_t* WhS = (uint16_t*)(ws);                 // fallback only
  uint16_t* WdS = (uint16_t*)(ws + 33554432);
  uint16_t* H0S = (uint16_t*)(ws + 37748736);
  uint16_t* Gsw = (uint16_t*)(ws + 38797312);
  float*    Part = (float*)(ws + 143654912);
  int*      flags = (int*)(ws + 160432128);

  cvt_wdec_kernel<<<512, 512, 0, stream>>>(Wdec, WdS, flags);
  enc_kernel<<<256, 512, 0, stream>>>(p0, Wenc, H0S);

  // persistent flag-synced RNN loop (cooperative launch for residency guarantee)
  const float* Whh_c = Whh;
  const uint16_t* H0S_c = H0S;
  void* args[7] = {(void*)&Whh_c, (void*)&H0S_c, (void*)&Gsw, (void*)&Part,
                   (void*)&v, (void*)&Wih, (void*)&flags};
  hipError_t e = hipLaunchCooperativeKernel(rnn_loop_kernel, dim3(256), dim3(512), args,
                                            (unsigned int)131072, stream);
  if (e != hipSuccess) {
    // fallback: per-step launches (round-1 path, ~1.96 ms class)
    (void)hipGetLastError();
    cvt_whh_kernel<<<4096, 512, 0, stream>>>(Whh, WhS);
    for (int t = 0; t < kT; t++) {
      const uint16_t* Asrc = (t == 0) ? H0S : (Gsw + (size_t)(t - 1) * 524288);
      stepmm_kernel<<<256, 512, 0, stream>>>(Asrc, WhS, Part);
      steptanh_kernel<<<256, 256, 0, stream>>>(Part, v, Wih, Gsw + (size_t)t * 524288, t);
    }
  }

  dec_kernel<<<416, 512, 0, stream>>>(Gsw, WdS, bdec, out);
}